// Round 10
// baseline (2653.640 us; speedup 1.0000x reference)
//
#include <hip/hip_runtime.h>

__device__ __forceinline__ float lrelu(float x) { return x >= 0.f ? x : 0.2f * x; }

typedef const __attribute__((address_space(1))) void* gas_ptr;
typedef __attribute__((address_space(3))) void* las_ptr;

// ---------------------------------------------------------------------------
// conv0: fp32 x (4,3,256,256) (half batch), w (64,3,3,3), s1 p1, +bias+lrelu
// -> ACTIVATED fp32 PADDED h0p (4,64,258,260), interior at (1,1)
// ---------------------------------------------------------------------------
__global__ __launch_bounds__(256) void conv0_k(const float* __restrict__ x,
                                               const float* __restrict__ w,
                                               const float* __restrict__ bias,
                                               float* __restrict__ out) {
    __shared__ float sIn[3][34][34];
    __shared__ float sW[27][16];
    const int H = 256;
    int tid = threadIdx.x, tx = tid & 31, ty = tid >> 5;
    int tX = (blockIdx.x & 7) * 32, tY = (blockIdx.x >> 3) * 32;
    int b = blockIdx.y, cog = blockIdx.z * 16;
    float acc[4][16] = {};
    const float* inB = x + (size_t)b * 3 * H * H;
    for (int idx = tid; idx < 3 * 1156; idx += 256) {
        int ci = idx / 1156, r = idx % 1156, iy = r / 34, ix = r % 34;
        int gy = tY - 1 + iy, gx = tX - 1 + ix;
        float v = 0.f;
        if ((unsigned)gy < 256u && (unsigned)gx < 256u)
            v = inB[(ci * H + gy) * H + gx];
        sIn[ci][iy][ix] = v;
    }
    for (int idx = tid; idx < 27 * 16; idx += 256) {
        int co = idx & 15, rest = idx >> 4;
        sW[rest][co] = w[(cog + co) * 27 + rest];
    }
    __syncthreads();
#pragma unroll
    for (int ci = 0; ci < 3; ci++)
#pragma unroll
        for (int dy = 0; dy < 3; dy++)
#pragma unroll
            for (int dx = 0; dx < 3; dx++) {
                float a0 = sIn[ci][ty + dy][tx + dx];
                float a1 = sIn[ci][ty + 8 + dy][tx + dx];
                float a2 = sIn[ci][ty + 16 + dy][tx + dx];
                float a3 = sIn[ci][ty + 24 + dy][tx + dx];
                const float* wp = sW[ci * 9 + dy * 3 + dx];
#pragma unroll
                for (int co = 0; co < 16; co++) {
                    float wv = wp[co];
                    acc[0][co] += a0 * wv; acc[1][co] += a1 * wv;
                    acc[2][co] += a2 * wv; acc[3][co] += a3 * wv;
                }
            }
    float* outB = out + (size_t)(b * 64 + cog) * 67080;   // 258*260
#pragma unroll
    for (int co = 0; co < 16; co++) {
        float bv = bias[cog + co];
#pragma unroll
        for (int r = 0; r < 4; r++)
            outB[(size_t)co * 67080 + (size_t)(tY + ty + 8 * r + 1) * 260 +
                 tX + tx + 1] = lrelu(acc[r][co] + bv);
    }
}

// ---------------------------------------------------------------------------
// Shuffle-based BN-stats epilogue for NWV-wave blocks.
// ---------------------------------------------------------------------------
template <int COG, int RPT, int NWV>
__device__ __forceinline__ void stats_epi(float (&acc)[RPT][COG], float2* sRed,
                                          double2* part, int cog, int slotBase,
                                          int S, int tid) {
    const int lane = tid & 63, wv = tid >> 6;
    float s[COG], q[COG];
#pragma unroll
    for (int c = 0; c < COG; c++) {
        float ss = 0.f, qq = 0.f;
#pragma unroll
        for (int j = 0; j < RPT; j++) { float v = acc[j][c]; ss += v; qq += v * v; }
        s[c] = ss; q[c] = qq;
    }
#pragma unroll
    for (int off = 32; off; off >>= 1)
#pragma unroll
        for (int c = 0; c < COG; c++) {
            s[c] += __shfl_xor(s[c], off);
            q[c] += __shfl_xor(q[c], off);
        }
    if (lane == 0)
#pragma unroll
        for (int c = 0; c < COG; c++) sRed[wv * COG + c] = make_float2(s[c], q[c]);
    __syncthreads();
    if (tid < COG) {
        double ss = 0.0, qq = 0.0;
#pragma unroll
        for (int wvi = 0; wvi < NWV; wvi++) {
            float2 p = sRed[wvi * COG + tid];
            ss += (double)p.x; qq += (double)p.y;
        }
        int slot = slotBase + blockIdx.y * gridDim.x + blockIdx.x;
        part[(size_t)(cog + tid) * S + slot] = make_double2(ss, qq);
    }
}

// ---------------------------------------------------------------------------
// 4x4 s2 conv (conv1, conv3): 128-thread blocks, 32x16 out tile, 4 out rows
// per thread (unchanged from R9).
// ---------------------------------------------------------------------------
template <int COG>
__global__ __launch_bounds__(128) void c4x4p_k(const float* __restrict__ in,
                                               const float* __restrict__ w,
                                               float* __restrict__ out,
                                               double2* __restrict__ part,
                                               int slotBase, int S,
                                               int Cin, int Cout, int Hin,
                                               int Hp, int Wp,
                                               int oHp, int oWp, int oOff) {
    constexpr int NSF4 = 34 * 17;             // 578 float4 per cin
    constexpr int NR = (NSF4 + 127) / 128;    // 5
    __shared__ float sIn[2][34 * 68];
    __shared__ float sW[2][16 * COG];
    __shared__ float2 sRed[2 * COG];
    const int Hout = Hin >> 1;
    const int tid = threadIdx.x, tx = tid & 31, ty = tid >> 5;   // ty 0..3
    const int tpr = Hout >> 5;                // x tiles (32 wide)
    const int tX = (blockIdx.x % tpr) * 32, tY = (blockIdx.x / tpr) * 16;
    const int b = blockIdx.y, cog = blockIdx.z * COG;
    const int HWin = Hp * Wp;
    const float* inB = in + (size_t)b * Cin * HWin;
    const int wvbase = tid & ~63;

    int gOff[NR]; int lOff[NR]; bool act[NR];
#pragma unroll
    for (int r = 0; r < NR; r++) {
        int idx = tid + r * 128;
        bool a = idx < NSF4;
        int row = idx / 17, c4 = idx % 17;
        gOff[r] = a ? ((2 * tY + row) * Wp + 2 * tX + 4 * c4) : 0;
        lOff[r] = (r * 128 + wvbase) * 4;
        act[r] = a;
    }
    const int wco = tid % COG, wt = tid / COG;      // 16*COG == 128 exactly
    const int wgo = ((cog + wco) * Cin) * 16 + wt;

    float acc[4][COG];
#pragma unroll
    for (int j = 0; j < 4; j++)
#pragma unroll
        for (int c = 0; c < COG; c++) acc[j][c] = 0.f;

#pragma unroll
    for (int r = 0; r < NR; r++)
        if (act[r])
            __builtin_amdgcn_global_load_lds((gas_ptr)(inB + gOff[r]),
                                             (las_ptr)(&sIn[0][lOff[r]]), 16, 0, 0);
    __builtin_amdgcn_global_load_lds((gas_ptr)(w + wgo),
                                     (las_ptr)(&sW[0][wvbase]), 4, 0, 0);
    __syncthreads();

    for (int k = 0; k < Cin; k++) {
        const int cur = k & 1, nb = cur ^ 1;
        const bool more = (k + 1) < Cin;
        if (more) {
            const float* p = inB + (size_t)(k + 1) * HWin;
#pragma unroll
            for (int r = 0; r < NR; r++)
                if (act[r])
                    __builtin_amdgcn_global_load_lds(
                        (gas_ptr)(p + gOff[r]),
                        (las_ptr)(&sIn[nb][lOff[r]]), 16, 0, 0);
            __builtin_amdgcn_global_load_lds(
                (gas_ptr)(w + wgo + (k + 1) * 16),
                (las_ptr)(&sW[nb][wvbase]), 4, 0, 0);
        }
        const float* sI = sIn[cur];
        const float* sw = sW[cur];
#pragma unroll
        for (int dy = 0; dy < 4; dy++)
#pragma unroll
            for (int dx = 0; dx < 4; dx++) {
                const float* bp = sI + (2 * ty + dy) * 68 + 2 * tx + dx;
                float a0 = bp[0];
                float a1 = bp[8 * 68];
                float a2 = bp[16 * 68];
                float a3 = bp[24 * 68];
                const float* wp = sw + (dy * 4 + dx) * COG;
#pragma unroll
                for (int c = 0; c < COG; c++) {
                    float wv = wp[c];
                    acc[0][c] += a0 * wv; acc[1][c] += a1 * wv;
                    acc[2][c] += a2 * wv; acc[3][c] += a3 * wv;
                }
            }
        __syncthreads();
    }

    float* outB = out + (size_t)(b * Cout + cog) * oHp * oWp;
#pragma unroll
    for (int c = 0; c < COG; c++)
#pragma unroll
        for (int r = 0; r < 4; r++)
            outB[(size_t)c * oHp * oWp +
                 (size_t)(tY + ty + 4 * r + oOff) * oWp + tX + tx + oOff] =
                acc[r][c];
    stats_epi<COG, 4, 2>(acc, sRed, part, cog, slotBase, S, tid);
}

// ---------------------------------------------------------------------------
// 3x3 s1 conv: 128-thread blocks, 32x32 out tile. NEW mapping: thread =
// 2 adjacent out cols x 4 rows (g=tid&15, ty8=tid>>4). Per ci: 6 rows x
// 4 cols loaded as 12 ds_read_b64 (was 30 scalar b32) — 2.5x fewer act
// LDS instructions; bank pattern 2-way max (free, m136). All 9 taps then
// register-resident. Staging identical to R9 (proven).
// ---------------------------------------------------------------------------
template <int COG>
__global__ __launch_bounds__(128) void c3x3_k(const float* __restrict__ in,
                                              const float* __restrict__ w,
                                              float* __restrict__ out,
                                              double2* __restrict__ part,
                                              int slotBase, int S,
                                              int Cin, int Cout, int H,
                                              int Hp, int Wp,
                                              int oHp, int oWp, int oOff) {
    constexpr int RS = 36;
    constexpr int ROWS = 34;                  // 32 out rows + 2 halo
    constexpr int CI = ROWS * RS;             // 1224
    constexpr int NSF4 = 2 * ROWS * 9;        // 612 float4 per 2-cin step
    constexpr int NR = (NSF4 + 127) / 128;    // 5
    constexpr int NWR = (18 * COG + 127) / 128;  // 2
    __shared__ float sIn[2][2 * CI];
    __shared__ float sW[2][18 * COG];
    __shared__ float2 sRed[2 * COG];
    const int tid = threadIdx.x;
    const int g = tid & 15, ty8 = tid >> 4;   // 16 col-pairs, 8 row-groups
    const int tpr = H >> 5;                   // x tiles (32 wide)
    const int tX = (blockIdx.x % tpr) * 32, tY = (blockIdx.x / tpr) * 32;
    const int b = blockIdx.y, cog = blockIdx.z * COG;
    const int HWin = Hp * Wp;
    const float* inB = in + (size_t)b * Cin * HWin;
    const int wvbase = tid & ~63;

    int gOff[NR]; int lOff[NR]; bool act[NR];
#pragma unroll
    for (int r = 0; r < NR; r++) {
        int idx = tid + r * 128;
        bool a = idx < NSF4;
        int ci = idx / (9 * ROWS), rem = idx % (9 * ROWS);
        int row = rem / 9, c4 = rem % 9;
        gOff[r] = a ? (ci * HWin + (tY + row) * Wp + tX + 4 * c4) : 0;
        lOff[r] = (r * 128 + wvbase) * 4;
        act[r] = a;
    }
    int wgo[NWR]; bool wact[NWR]; int wlo[NWR];
#pragma unroll
    for (int r = 0; r < NWR; r++) {
        int widx = tid + r * 128;
        bool a = widx < 18 * COG;
        int co = widx % COG, rest = widx / COG;
        int ci = rest / 9, t = rest % 9;
        wgo[r] = a ? (((cog + co) * Cin + ci) * 9 + t) : 0;
        wlo[r] = r * 128 + wvbase;
        wact[r] = a;
    }

    float acc[8][COG];                        // [row j*2 + col cc][cout]
#pragma unroll
    for (int j = 0; j < 8; j++)
#pragma unroll
        for (int c = 0; c < COG; c++) acc[j][c] = 0.f;

    const int steps = Cin >> 1;

    auto STAGE = [&](int t, int buf) {
        const float* p = inB + (size_t)(2 * t) * HWin;
#pragma unroll
        for (int r = 0; r < NR; r++)
            if (act[r])
                __builtin_amdgcn_global_load_lds(
                    (gas_ptr)(p + gOff[r]),
                    (las_ptr)(&sIn[buf][lOff[r]]), 16, 0, 0);
        const float* wp2 = w + (size_t)(2 * t) * 9;
#pragma unroll
        for (int r = 0; r < NWR; r++)
            if (wact[r])
                __builtin_amdgcn_global_load_lds(
                    (gas_ptr)(wp2 + wgo[r]),
                    (las_ptr)(&sW[buf][wlo[r]]), 4, 0, 0);
    };

    STAGE(0, 0);
    __syncthreads();
    for (int k = 0; k < steps; k++) {
        const int cur = k & 1, nb = cur ^ 1;
        if (k + 1 < steps) STAGE(k + 1, nb);
        const float* sI = sIn[cur];
        const float* sw = sW[cur];
#pragma unroll
        for (int ci = 0; ci < 2; ci++) {
            const float* bp = sI + ci * CI + (4 * ty8) * RS + 2 * g;
            float a[6][4];
#pragma unroll
            for (int j = 0; j < 6; j++) {
                float2 q0 = *(const float2*)(bp + j * RS);
                float2 q1 = *(const float2*)(bp + j * RS + 2);
                a[j][0] = q0.x; a[j][1] = q0.y;
                a[j][2] = q1.x; a[j][3] = q1.y;
            }
#pragma unroll
            for (int dy = 0; dy < 3; dy++)
#pragma unroll
                for (int dx = 0; dx < 3; dx++) {
                    const float* wp = sw + (ci * 9 + dy * 3 + dx) * COG;
#pragma unroll
                    for (int c = 0; c < COG; c++) {
                        float wv = wp[c];
#pragma unroll
                        for (int j = 0; j < 4; j++) {
                            acc[j * 2 + 0][c] += a[j + dy][0 + dx] * wv;
                            acc[j * 2 + 1][c] += a[j + dy][1 + dx] * wv;
                        }
                    }
                }
        }
        __syncthreads();
    }

    float* outB = out + (size_t)(b * Cout + cog) * oHp * oWp;
#pragma unroll
    for (int c = 0; c < COG; c++)
#pragma unroll
        for (int j = 0; j < 4; j++)
#pragma unroll
            for (int cc = 0; cc < 2; cc++)
                outB[(size_t)c * oHp * oWp +
                     (size_t)(tY + 4 * ty8 + j + oOff) * oWp +
                     tX + 2 * g + cc + oOff] = acc[j * 2 + cc][c];
    stats_epi<COG, 8, 2>(acc, sRed, part, cog, slotBase, S, tid);
}

// ---------------------------------------------------------------------------
// bnfin: parallel fp64 combine — one block per channel, shuffle reduce
// (was 1 block total: ~6 serial latency-bound dispatches of glue).
// ---------------------------------------------------------------------------
__global__ __launch_bounds__(256) void bnfin_k(const double2* __restrict__ part,
                                               int S, int C, double invN,
                                               const float* __restrict__ g,
                                               const float* __restrict__ bb,
                                               float2* __restrict__ ss) {
    __shared__ double2 red[4];
    const int c = blockIdx.x, tid = threadIdx.x;
    double sum = 0.0, sq = 0.0;
    for (int s = tid; s < S; s += 256) {
        double2 p = part[(size_t)c * S + s];
        sum += p.x; sq += p.y;
    }
#pragma unroll
    for (int off = 32; off; off >>= 1) {
        sum += __shfl_xor(sum, off);
        sq += __shfl_xor(sq, off);
    }
    if ((tid & 63) == 0) red[tid >> 6] = make_double2(sum, sq);
    __syncthreads();
    if (tid == 0) {
        double s2 = 0.0, q2 = 0.0;
#pragma unroll
        for (int wv = 0; wv < 4; wv++) { s2 += red[wv].x; q2 += red[wv].y; }
        double m = s2 * invN;
        double v = q2 * invN - m * m;
        double sc = (double)g[c] / sqrt(v + 1e-5);
        ss[c] = make_float2((float)sc, (float)((double)bb[c] - m * sc));
    }
}

// ---------------------------------------------------------------------------
// bnact: zero padded border; if ss != nullptr also transform interior with
// lrelu(sc*x+sh) in place. One block per (b,c) plane, C power of two.
// ---------------------------------------------------------------------------
__global__ __launch_bounds__(256) void bnact_k(float* __restrict__ p,
                                               const float2* __restrict__ ss,
                                               int C, int H, int W,
                                               int Hp, int Wp) {
    int pc = blockIdx.x;
    int c = pc & (C - 1);
    float2 t = ss ? ss[c] : make_float2(1.f, 0.f);
    bool xf = (ss != nullptr);
    float* pl = p + (size_t)pc * Hp * Wp;
    int n = Hp * Wp;
    for (int i = threadIdx.x; i < n; i += 256) {
        int y = i / Wp, x = i - y * Wp;
        bool inter = (y >= 1) && (y <= H) && (x >= 1) && (x <= W);
        if (!inter) pl[i] = 0.f;
        else if (xf) { float v = pl[i]; pl[i] = lrelu(t.x * v + t.y); }
    }
}

// ---------------------------------------------------------------------------
// h6 raw (8,256,64,64) + BN6+lrelu -> tok (8,4096,256)
// ---------------------------------------------------------------------------
__global__ __launch_bounds__(256) void transp_k(const float* __restrict__ h6,
                                                const float2* __restrict__ ss,
                                                float* __restrict__ tok) {
    __shared__ float sT[32][33];
    int tx = threadIdx.x & 31, ty = threadIdx.x >> 5;
    int n0 = blockIdx.x * 32, d0 = blockIdx.y * 32, b = blockIdx.z;
    const float* hb = h6 + ((size_t)b * 256 + d0) * 4096 + n0;
#pragma unroll
    for (int r = 0; r < 4; r++) {
        int d = ty + 8 * r;
        float2 t = ss[d0 + d];
        sT[d][tx] = lrelu(t.x * hb[d * 4096 + tx] + t.y);
    }
    __syncthreads();
    float* tb = tok + ((size_t)b * 4096 + n0) * 256 + d0;
#pragma unroll
    for (int r = 0; r < 4; r++) {
        int n = ty + 8 * r;
        tb[n * 256 + tx] = sT[tx][n];
    }
}

// ---------------------------------------------------------------------------
// Token stage: gating argmax, selected-expert body slice, ortho, cls MLP.
// ---------------------------------------------------------------------------
__global__ __launch_bounds__(256) void token_k(const float* __restrict__ tok,
                                               const float* __restrict__ wg,
                                               const float* __restrict__ bw,
                                               const float* __restrict__ bb,
                                               const float* __restrict__ ow,
                                               const float* __restrict__ w1,
                                               const float* __restrict__ b1,
                                               const float* __restrict__ w2,
                                               const float* __restrict__ b2,
                                               float* __restrict__ outp) {
    __shared__ float sf[4][256];
    const int tid = threadIdx.x, wave = tid >> 6, l = tid & 63;
    const int t = blockIdx.x * 4 + wave;
    const float4 tv = reinterpret_cast<const float4*>(tok + (size_t)t * 256)[l];
    sf[wave][4 * l + 0] = tv.x; sf[wave][4 * l + 1] = tv.y;
    sf[wave][4 * l + 2] = tv.z; sf[wave][4 * l + 3] = tv.w;

    float lg[12];
#pragma unroll
    for (int e = 0; e < 12; e++) lg[e] = 0.f;
    const float tj[4] = {tv.x, tv.y, tv.z, tv.w};
#pragma unroll
    for (int j = 0; j < 4; j++) {
        const float* wr = wg + (4 * l + j) * 12;
#pragma unroll
        for (int e = 0; e < 12; e++) lg[e] += tj[j] * wr[e];
    }
#pragma unroll
    for (int off = 32; off > 0; off >>= 1) {
#pragma unroll
        for (int e = 0; e < 12; e++) lg[e] += __shfl_xor(lg[e], off);
    }
    int idx = 0; float best = lg[0];
#pragma unroll
    for (int e = 1; e < 12; e++)
        if (lg[e] > best) { best = lg[e]; idx = e; }
    const int cb = idx * 256;

    float f0 = 0.f, f1 = 0.f, f2 = 0.f, f3 = 0.f;
    const float* bwp = bw + cb + 4 * l;
#pragma unroll 4
    for (int d = 0; d < 256; d++) {
        const float td = sf[wave][d];
        const float4 wv = *reinterpret_cast<const float4*>(bwp + (size_t)d * 3072);
        f0 += td * wv.x; f1 += td * wv.y;
        f2 += td * wv.z; f3 += td * wv.w;
    }
    float fj[4] = {f0, f1, f2, f3};
#pragma unroll
    for (int j = 0; j < 4; j++) {
        int jj = cb + 4 * l + j;
        float v = lrelu(fj[j] + bb[jj]);
        v = lrelu(v * ow[jj]);
        sf[wave][4 * l + j] = v;
    }

    float o = 0.f;
    if (l < 32) {
        float h = b1[l];
#pragma unroll 4
        for (int j = 0; j < 256; j++) h += sf[wave][j] * w1[j * 32 + l];
        h = lrelu(h);
        o = h * w2[l];
    }
    o += __shfl_xor(o, 16); o += __shfl_xor(o, 8); o += __shfl_xor(o, 4);
    o += __shfl_xor(o, 2);  o += __shfl_xor(o, 1);
    if (l == 0) outp[t] = o + b2[0];
}

// ---------------------------------------------------------------------------
extern "C" void kernel_launch(void* const* d_in, const int* in_sizes, int n_in,
                              void* d_out, int out_size, void* d_ws, size_t ws_size,
                              hipStream_t stream) {
    const float* x   = (const float*)d_in[0];
    const float* w0  = (const float*)d_in[1];
    const float* b0  = (const float*)d_in[2];
    const float* w1  = (const float*)d_in[3];
    const float* g1  = (const float*)d_in[4];
    const float* be1 = (const float*)d_in[5];
    const float* w2  = (const float*)d_in[6];
    const float* g2  = (const float*)d_in[7];
    const float* be2 = (const float*)d_in[8];
    const float* w3  = (const float*)d_in[9];
    const float* g3  = (const float*)d_in[10];
    const float* be3 = (const float*)d_in[11];
    const float* w4  = (const float*)d_in[12];
    const float* g4  = (const float*)d_in[13];
    const float* be4 = (const float*)d_in[14];
    const float* w5  = (const float*)d_in[15];
    const float* g5  = (const float*)d_in[16];
    const float* be5 = (const float*)d_in[17];
    const float* w6  = (const float*)d_in[18];
    const float* g6  = (const float*)d_in[19];
    const float* be6 = (const float*)d_in[20];
    const float* wg  = (const float*)d_in[21];
    const float* bw  = (const float*)d_in[22];
    const float* bbp = (const float*)d_in[23];
    const float* owp = (const float*)d_in[24];
    const float* cw1 = (const float*)d_in[25];
    const float* cb1 = (const float*)d_in[26];
    const float* cw2 = (const float*)d_in[27];
    const float* cb2 = (const float*)d_in[28];

    char* W = (char*)d_ws;
    float2* ssb = (float2*)W;                 // ss tables in [0,16K)
    float2* ss1 = ssb;
    float2* ss2 = ssb + 64;
    float2* ss3 = ssb + 192;
    float2* ss4 = ssb + 320;
    float2* ss5 = ssb + 576;
    float2* ss6 = ssb + 832;
    double2* part = (double2*)(W + 16384);    // 256 KiB cap (conv1: 64x256)

    // Big region @278528 — R1-proven buffer plan (span 105.71 MB).
    char* BIG = W + 278528;
    float* h0p = (float*)(BIG);               // (4,64,258,260) 68.69 MB
    float* h1p = (float*)(BIG + 70287360);    // (8,64,130,132) 35.14 MB
    float* h2p = (float*)(BIG);               // (8,128,130,132) 70.29 MB
    float* h3p = (float*)(BIG + 70287360);    // (8,128,66,68) 18.4 MB
    float* h4p = (float*)(BIG);               // (8,256,66,68) 36.77 MB
    float* h5p = (float*)(BIG + 36765696);    // (8,256,66,68)
    float* h6  = (float*)(BIG);               // (8,256,64,64) 32 MiB
    float* tok = (float*)(BIG + 36765696);    // (8,4096,256) 32 MiB

    // zero h0p borders once (conv0 halves only write interior)
    bnact_k<<<256, 256, 0, stream>>>(h0p, nullptr, 64, 256, 256, 258, 260);
    // conv0 (padded out) + conv1 per half (128-thr blocks, 32x16 tiles)
    for (int half = 0; half < 2; half++) {
        conv0_k<<<dim3(64, 4, 4), 256, 0, stream>>>(
            x + (size_t)half * 4 * 3 * 65536, w0, b0, h0p);
        c4x4p_k<8><<<dim3(32, 4, 8), 128, 0, stream>>>(
            h0p, w1, h1p + (size_t)half * 4 * 64 * 17160, part, half * 128, 256,
            64, 64, 256, 258, 260, 130, 132, 1);
    }
    bnfin_k<<<64, 256, 0, stream>>>(part, 256, 64, 1.0 / 131072.0, g1, be1, ss1);
    bnact_k<<<512, 256, 0, stream>>>(h1p, ss1, 64, 128, 128, 130, 132);
    // conv2 3x3 (32x32 tiles, 128 thr): 2048 blocks, S=128
    c3x3_k<8><<<dim3(16, 8, 16), 128, 0, stream>>>(
        h1p, w2, h2p, part, 0, 128, 64, 128, 128, 130, 132, 130, 132, 1);
    bnfin_k<<<128, 256, 0, stream>>>(part, 128, 128, 1.0 / 131072.0, g2, be2, ss2);
    bnact_k<<<1024, 256, 0, stream>>>(h2p, ss2, 128, 128, 128, 130, 132);
    // conv3 4x4 s2 (32x16 tiles, 128 thr): 1024 blocks, S=64
    c4x4p_k<8><<<dim3(8, 8, 16), 128, 0, stream>>>(
        h2p, w3, h3p, part, 0, 64, 128, 128, 128, 130, 132, 66, 68, 1);
    bnfin_k<<<128, 256, 0, stream>>>(part, 64, 128, 1.0 / 32768.0, g3, be3, ss3);
    bnact_k<<<1024, 256, 0, stream>>>(h3p, ss3, 128, 64, 64, 66, 68);
    // conv4 3x3 (32x32 tiles, 128 thr): 1024 blocks, S=32
    c3x3_k<8><<<dim3(4, 8, 32), 128, 0, stream>>>(
        h3p, w4, h4p, part, 0, 32, 128, 256, 64, 66, 68, 66, 68, 1);
    bnfin_k<<<256, 256, 0, stream>>>(part, 32, 256, 1.0 / 32768.0, g4, be4, ss4);
    bnact_k<<<2048, 256, 0, stream>>>(h4p, ss4, 256, 64, 64, 66, 68);
    // conv5 3x3: 1024 blocks
    c3x3_k<8><<<dim3(4, 8, 32), 128, 0, stream>>>(
        h4p, w5, h5p, part, 0, 32, 256, 256, 64, 66, 68, 66, 68, 1);
    bnfin_k<<<256, 256, 0, stream>>>(part, 32, 256, 1.0 / 32768.0, g5, be5, ss5);
    bnact_k<<<2048, 256, 0, stream>>>(h5p, ss5, 256, 64, 64, 66, 68);
    // conv6 3x3: h5p -> h6 unpadded
    c3x3_k<8><<<dim3(4, 8, 32), 128, 0, stream>>>(
        h5p, w6, h6, part, 0, 32, 256, 256, 64, 66, 68, 64, 64, 0);
    bnfin_k<<<256, 256, 0, stream>>>(part, 32, 256, 1.0 / 32768.0, g6, be6, ss6);
    // transpose + BN6 + lrelu -> tok
    transp_k<<<dim3(128, 8, 8), 256, 0, stream>>>(h6, ss6, tok);
    // token stage -> out fp32 (8,4096,1)
    token_k<<<8192, 256, 0, stream>>>(tok, wg, bw, bbp, owp, cw1, cb1, cw2, cb2,
                                      (float*)d_out);
}

// Round 11
// 2538.027 us; speedup vs baseline: 1.0456x; 1.0456x over previous
//
#include <hip/hip_runtime.h>

__device__ __forceinline__ float lrelu(float x) { return x >= 0.f ? x : 0.2f * x; }

typedef const __attribute__((address_space(1))) void* gas_ptr;
typedef __attribute__((address_space(3))) void* las_ptr;

// ---------------------------------------------------------------------------
// conv0: fp32 x (4,3,256,256) (half batch), w (64,3,3,3), s1 p1, +bias+lrelu
// -> ACTIVATED fp32 PADDED h0p (4,64,258,260), interior at (1,1)
// ---------------------------------------------------------------------------
__global__ __launch_bounds__(256) void conv0_k(const float* __restrict__ x,
                                               const float* __restrict__ w,
                                               const float* __restrict__ bias,
                                               float* __restrict__ out) {
    __shared__ float sIn[3][34][34];
    __shared__ float sW[27][16];
    const int H = 256;
    int tid = threadIdx.x, tx = tid & 31, ty = tid >> 5;
    int tX = (blockIdx.x & 7) * 32, tY = (blockIdx.x >> 3) * 32;
    int b = blockIdx.y, cog = blockIdx.z * 16;
    float acc[4][16] = {};
    const float* inB = x + (size_t)b * 3 * H * H;
    for (int idx = tid; idx < 3 * 1156; idx += 256) {
        int ci = idx / 1156, r = idx % 1156, iy = r / 34, ix = r % 34;
        int gy = tY - 1 + iy, gx = tX - 1 + ix;
        float v = 0.f;
        if ((unsigned)gy < 256u && (unsigned)gx < 256u)
            v = inB[(ci * H + gy) * H + gx];
        sIn[ci][iy][ix] = v;
    }
    for (int idx = tid; idx < 27 * 16; idx += 256) {
        int co = idx & 15, rest = idx >> 4;
        sW[rest][co] = w[(cog + co) * 27 + rest];
    }
    __syncthreads();
#pragma unroll
    for (int ci = 0; ci < 3; ci++)
#pragma unroll
        for (int dy = 0; dy < 3; dy++)
#pragma unroll
            for (int dx = 0; dx < 3; dx++) {
                float a0 = sIn[ci][ty + dy][tx + dx];
                float a1 = sIn[ci][ty + 8 + dy][tx + dx];
                float a2 = sIn[ci][ty + 16 + dy][tx + dx];
                float a3 = sIn[ci][ty + 24 + dy][tx + dx];
                const float* wp = sW[ci * 9 + dy * 3 + dx];
#pragma unroll
                for (int co = 0; co < 16; co++) {
                    float wv = wp[co];
                    acc[0][co] += a0 * wv; acc[1][co] += a1 * wv;
                    acc[2][co] += a2 * wv; acc[3][co] += a3 * wv;
                }
            }
    float* outB = out + (size_t)(b * 64 + cog) * 67080;   // 258*260
#pragma unroll
    for (int co = 0; co < 16; co++) {
        float bv = bias[cog + co];
#pragma unroll
        for (int r = 0; r < 4; r++)
            outB[(size_t)co * 67080 + (size_t)(tY + ty + 8 * r + 1) * 260 +
                 tX + tx + 1] = lrelu(acc[r][co] + bv);
    }
}

// ---------------------------------------------------------------------------
// Shuffle-based BN-stats epilogue: per-channel (sum, sumsq) partials.
// ---------------------------------------------------------------------------
template <int COG, int RPT>
__device__ __forceinline__ void stats_epi(float (&acc)[RPT][COG], float2* sRed,
                                          double2* part, int cog, int slotBase,
                                          int S, int tid) {
    const int lane = tid & 63, wv = tid >> 6;
    float s[COG], q[COG];
#pragma unroll
    for (int c = 0; c < COG; c++) {
        float ss = 0.f, qq = 0.f;
#pragma unroll
        for (int j = 0; j < RPT; j++) { float v = acc[j][c]; ss += v; qq += v * v; }
        s[c] = ss; q[c] = qq;
    }
#pragma unroll
    for (int off = 32; off; off >>= 1)
#pragma unroll
        for (int c = 0; c < COG; c++) {
            s[c] += __shfl_xor(s[c], off);
            q[c] += __shfl_xor(q[c], off);
        }
    if (lane == 0)
#pragma unroll
        for (int c = 0; c < COG; c++) sRed[wv * COG + c] = make_float2(s[c], q[c]);
    __syncthreads();
    if (tid < COG) {
        double ss = 0.0, qq = 0.0;
#pragma unroll
        for (int wvi = 0; wvi < 4; wvi++) {
            float2 p = sRed[wvi * COG + tid];
            ss += (double)p.x; qq += (double)p.y;
        }
        int slot = slotBase + blockIdx.y * gridDim.x + blockIdx.x;
        part[(size_t)(cog + tid) * S + slot] = make_double2(ss, qq);
    }
}

// ---------------------------------------------------------------------------
// 4x4 s2 conv (conv1, conv3): R8 structure verbatim (LDS weight staging,
// 2-buffer global_load_lds, __syncthreads), shuffle stats epilogue.
// ---------------------------------------------------------------------------
template <int COG>
__global__ __launch_bounds__(256) void c4x4p_k(const float* __restrict__ in,
                                               const float* __restrict__ w,
                                               float* __restrict__ out,
                                               double2* __restrict__ part,
                                               int slotBase, int S,
                                               int Cin, int Cout, int Hin,
                                               int Hp, int Wp,
                                               int oHp, int oWp, int oOff) {
    __shared__ float sIn[2][4488];            // 66 rows x 68 cols
    __shared__ float sW[2][16 * COG];
    __shared__ float2 sRed[4 * COG];
    const int Hout = Hin >> 1;
    const int tid = threadIdx.x, tx = tid & 31, ty = tid >> 5;
    const int tpr = Hout >> 5;
    const int tX = (blockIdx.x % tpr) * 32, tY = (blockIdx.x / tpr) * 32;
    const int b = blockIdx.y, cog = blockIdx.z * COG;
    const int HWin = Hp * Wp;
    const float* inB = in + (size_t)b * Cin * HWin;
    const int wvbase = tid & ~63;

    int gOff[5]; int lOff[5]; bool act[5];
#pragma unroll
    for (int r = 0; r < 5; r++) {
        int idx = tid + r * 256;
        bool a = idx < 1122;                  // 66 rows x 17 float4
        int row = idx / 17, c4 = idx % 17;
        gOff[r] = a ? ((2 * tY + row) * Wp + 2 * tX + 4 * c4) : 0;
        lOff[r] = (r * 256 + wvbase) * 4;
        act[r] = a;
    }
    const int wco = tid % COG, wt = tid / COG;
    const int wgo = ((cog + wco) * Cin) * 16 + wt;
    const bool wact = tid < 16 * COG;

    float acc[4][COG];
#pragma unroll
    for (int j = 0; j < 4; j++)
#pragma unroll
        for (int c = 0; c < COG; c++) acc[j][c] = 0.f;

#pragma unroll
    for (int r = 0; r < 5; r++)
        if (act[r])
            __builtin_amdgcn_global_load_lds((gas_ptr)(inB + gOff[r]),
                                             (las_ptr)(&sIn[0][lOff[r]]), 16, 0, 0);
    if (wact)
        __builtin_amdgcn_global_load_lds((gas_ptr)(w + wgo),
                                         (las_ptr)(&sW[0][wvbase]), 4, 0, 0);
    __syncthreads();

    for (int k = 0; k < Cin; k++) {
        const int cur = k & 1, nb = cur ^ 1;
        const bool more = (k + 1) < Cin;
        if (more) {
            const float* p = inB + (size_t)(k + 1) * HWin;
#pragma unroll
            for (int r = 0; r < 5; r++)
                if (act[r])
                    __builtin_amdgcn_global_load_lds(
                        (gas_ptr)(p + gOff[r]),
                        (las_ptr)(&sIn[nb][lOff[r]]), 16, 0, 0);
            if (wact)
                __builtin_amdgcn_global_load_lds(
                    (gas_ptr)(w + wgo + (k + 1) * 16),
                    (las_ptr)(&sW[nb][wvbase]), 4, 0, 0);
        }
        const float* sI = sIn[cur];
        const float* sw = sW[cur];
#pragma unroll
        for (int dy = 0; dy < 4; dy++)
#pragma unroll
            for (int dx = 0; dx < 4; dx++) {
                const float* bp = sI + (2 * ty + dy) * 68 + 2 * tx + dx;
                float a0 = bp[0];
                float a1 = bp[16 * 68];
                float a2 = bp[32 * 68];
                float a3 = bp[48 * 68];
                const float* wp = sw + (dy * 4 + dx) * COG;
#pragma unroll
                for (int c = 0; c < COG; c++) {
                    float wv = wp[c];
                    acc[0][c] += a0 * wv; acc[1][c] += a1 * wv;
                    acc[2][c] += a2 * wv; acc[3][c] += a3 * wv;
                }
            }
        __syncthreads();
    }

    float* outB = out + (size_t)(b * Cout + cog) * oHp * oWp;
#pragma unroll
    for (int c = 0; c < COG; c++)
#pragma unroll
        for (int r = 0; r < 4; r++)
            outB[(size_t)c * oHp * oWp +
                 (size_t)(tY + ty + 8 * r + oOff) * oWp + tX + tx + oOff] =
                acc[r][c];
    stats_epi<COG, 4>(acc, sRed, part, cog, slotBase, S, tid);
}

// ---------------------------------------------------------------------------
// 3x3 s1 conv, 32 wide x 64 tall tile, 8 out rows per thread (R8 verbatim).
// PIPE=false: 2-buffer __syncthreads (conv2). PIPE=true: 3-buffer rotation
// + counted vmcnt(6) + raw s_barrier (conv4/5/6).
// ---------------------------------------------------------------------------
template <int COG, bool PIPE>
__global__ __launch_bounds__(256) void c3x3_k(const float* __restrict__ in,
                                              const float* __restrict__ w,
                                              float* __restrict__ out,
                                              double2* __restrict__ part,
                                              int slotBase, int S,
                                              int Cin, int Cout, int H,
                                              int Hp, int Wp,
                                              int oHp, int oWp, int oOff) {
    constexpr int RS = 36;
    constexpr int ROWS = 66;                  // 64 out rows + 2 halo
    constexpr int CI = ROWS * RS;             // 2376
    constexpr int NSF4 = 2 * ROWS * 9;        // 1188 float4 per 2-cin step
    constexpr int NR = 5;
    constexpr int NBUF = PIPE ? 3 : 2;
    __shared__ float sIn[NBUF][2 * CI];
    __shared__ float sW[NBUF][18 * COG];
    __shared__ float2 sRed[4 * COG];
    __shared__ alignas(16) float sDummy[64];
    const int tid = threadIdx.x, tx = tid & 31, ty = tid >> 5;
    const bool lane0 = (tid & 63) == 0;
    const int tpr = H >> 5;                   // x tiles (width 32)
    const int tX = (blockIdx.x % tpr) * 32, tY = (blockIdx.x / tpr) * 64;
    const int b = blockIdx.y, cog = blockIdx.z * COG;
    const int HWin = Hp * Wp;
    const float* inB = in + (size_t)b * Cin * HWin;
    const int wvbase = tid & ~63;

    int gOff[NR]; int lOff[NR]; bool act[NR]; bool aw[NR];
#pragma unroll
    for (int r = 0; r < NR; r++) {
        int idx = tid + r * 256;
        act[r] = idx < NSF4;
        aw[r] = (r * 256 + wvbase) < NSF4;
        int ci = idx / (9 * ROWS), rem = idx % (9 * ROWS);
        int row = rem / 9, c4 = rem % 9;
        gOff[r] = act[r] ? (ci * HWin + (tY + row) * Wp + tX + 4 * c4) : 0;
        lOff[r] = (r * 256 + wvbase) * 4;
    }
    const bool wact = tid < 18 * COG;
    const bool waw = wvbase < 18 * COG;
    int wgo;
    {
        int co = tid % COG, rest = tid / COG;
        int ci = rest / 9, t = rest % 9;
        wgo = ((cog + co) * Cin + ci) * 9 + t;
    }

    float acc[8][COG];
#pragma unroll
    for (int j = 0; j < 8; j++)
#pragma unroll
        for (int c = 0; c < COG; c++) acc[j][c] = 0.f;

    const int steps = Cin >> 1;

    auto STAGE = [&](int t, int buf) {
        const float* p = inB + (size_t)(2 * t) * HWin;
#pragma unroll
        for (int r = 0; r < NR; r++) {
            if constexpr (PIPE) {
                float* dst = act[r] ? &sIn[buf][lOff[r]] : sDummy;
                const float* src = act[r] ? (p + gOff[r]) : p;
                if (act[r] || (!aw[r] && lane0))
                    __builtin_amdgcn_global_load_lds((gas_ptr)src, (las_ptr)dst,
                                                     16, 0, 0);
            } else {
                if (act[r])
                    __builtin_amdgcn_global_load_lds(
                        (gas_ptr)(p + gOff[r]),
                        (las_ptr)(&sIn[buf][lOff[r]]), 16, 0, 0);
            }
        }
        {
            const float* wsrc = w + (size_t)(2 * t) * 9 + wgo;
            if constexpr (PIPE) {
                const float* src = wact ? wsrc : w;
                float* dst = wact ? &sW[buf][wvbase] : sDummy;
                if (wact || (!waw && lane0))
                    __builtin_amdgcn_global_load_lds((gas_ptr)src, (las_ptr)dst,
                                                     4, 0, 0);
            } else {
                if (wact)
                    __builtin_amdgcn_global_load_lds(
                        (gas_ptr)wsrc, (las_ptr)(&sW[buf][wvbase]), 4, 0, 0);
            }
        }
    };

    auto COMPUTE = [&](int buf) {
        const float* sI = sIn[buf];
        const float* sw = sW[buf];
#pragma unroll
        for (int ci = 0; ci < 2; ci++)
#pragma unroll
            for (int dx = 0; dx < 3; dx++) {
                const float* bp = sI + ci * CI + (8 * ty) * RS + tx + dx;
                float a[10];
#pragma unroll
                for (int j = 0; j < 10; j++) a[j] = bp[j * RS];
#pragma unroll
                for (int dy = 0; dy < 3; dy++) {
                    const float* wp = sw + (ci * 9 + dy * 3 + dx) * COG;
#pragma unroll
                    for (int c = 0; c < COG; c++) {
                        float wv = wp[c];
#pragma unroll
                        for (int j = 0; j < 8; j++)
                            acc[j][c] += a[j + dy] * wv;
                    }
                }
            }
    };

    if constexpr (PIPE) {
        STAGE(0, 0);
        STAGE(1, 1);
        int cur = 0, nx2 = 2;
        for (int k = 0; k < steps; k++) {
            if (k < steps - 1) asm volatile("s_waitcnt vmcnt(6)" ::: "memory");
            else               asm volatile("s_waitcnt vmcnt(0)" ::: "memory");
            __builtin_amdgcn_sched_barrier(0);
            __builtin_amdgcn_s_barrier();
            __builtin_amdgcn_sched_barrier(0);
            if (k + 2 < steps) STAGE(k + 2, nx2);
            COMPUTE(cur);
            cur = (cur == 2) ? 0 : cur + 1;
            nx2 = (nx2 == 2) ? 0 : nx2 + 1;
        }
        __syncthreads();                      // protect sRed/stats reuse
    } else {
        STAGE(0, 0);
        __syncthreads();
        for (int k = 0; k < steps; k++) {
            const int cur = k & 1, nb = cur ^ 1;
            if (k + 1 < steps) STAGE(k + 1, nb);
            COMPUTE(cur);
            __syncthreads();
        }
    }

    float* outB = out + (size_t)(b * Cout + cog) * oHp * oWp;
#pragma unroll
    for (int c = 0; c < COG; c++)
#pragma unroll
        for (int j = 0; j < 8; j++)
            outB[(size_t)c * oHp * oWp +
                 (size_t)(tY + 8 * ty + j + oOff) * oWp + tX + tx + oOff] =
                acc[j][c];
    stats_epi<COG, 8>(acc, sRed, part, cog, slotBase, S, tid);
}

// ---------------------------------------------------------------------------
// bnact: FUSED bnfin — each block reduces its channel's (sum,sumsq)
// partials in-block (S <= 128 double2 loads, trivial), computes
// (scale, shift), then zeroes the padded border and transforms the
// interior with lrelu(sc*x+sh). part==nullptr -> border-zero only.
// Removes 6 serial bnfin_k launches from the critical path.
// ---------------------------------------------------------------------------
__global__ __launch_bounds__(256) void bnact_k(float* __restrict__ p,
                                               const double2* __restrict__ part,
                                               int S, double invN,
                                               const float* __restrict__ g,
                                               const float* __restrict__ bb,
                                               int C, int H, int W,
                                               int Hp, int Wp) {
    __shared__ double2 red[4];
    __shared__ float2 sSS;
    int pc = blockIdx.x;
    int c = pc & (C - 1);
    int tid = threadIdx.x;
    const bool xf = (part != nullptr);
    if (xf) {
        double sum = 0.0, sq = 0.0;
        for (int s = tid; s < S; s += 256) {
            double2 pp = part[(size_t)c * S + s];
            sum += pp.x; sq += pp.y;
        }
#pragma unroll
        for (int off = 32; off; off >>= 1) {
            sum += __shfl_xor(sum, off);
            sq += __shfl_xor(sq, off);
        }
        if ((tid & 63) == 0) red[tid >> 6] = make_double2(sum, sq);
        __syncthreads();
        if (tid == 0) {
            double s2 = 0.0, q2 = 0.0;
#pragma unroll
            for (int wv = 0; wv < 4; wv++) { s2 += red[wv].x; q2 += red[wv].y; }
            double m = s2 * invN;
            double v = q2 * invN - m * m;
            double sc = (double)g[c] / sqrt(v + 1e-5);
            sSS = make_float2((float)sc, (float)((double)bb[c] - m * sc));
        }
        __syncthreads();
    }
    float2 t = xf ? sSS : make_float2(1.f, 0.f);
    float* pl = p + (size_t)pc * Hp * Wp;
    int n = Hp * Wp;
    for (int i = tid; i < n; i += 256) {
        int y = i / Wp, x = i - y * Wp;
        bool inter = (y >= 1) && (y <= H) && (x >= 1) && (x <= W);
        if (!inter) pl[i] = 0.f;
        else if (xf) { float v = pl[i]; pl[i] = lrelu(t.x * v + t.y); }
    }
}

// ---------------------------------------------------------------------------
// transp: h6 raw (8,256,64,64) + FUSED BN6 stats (S=16) + lrelu
// -> tok (8,4096,256). Per block: reduce partials for its 32 channels
// (thread = (d, s): d=tid>>3 channel-in-group, s=tid&7 slot-pair).
// ---------------------------------------------------------------------------
__global__ __launch_bounds__(256) void transp_k(const float* __restrict__ h6,
                                                const double2* __restrict__ part,
                                                double invN,
                                                const float* __restrict__ g,
                                                const float* __restrict__ bb,
                                                float* __restrict__ tok) {
    __shared__ float sT[32][33];
    __shared__ float2 sSS[32];
    int tid = threadIdx.x;
    int tx = tid & 31, ty = tid >> 5;
    int n0 = blockIdx.x * 32, d0 = blockIdx.y * 32, b = blockIdx.z;
    {
        int d = tid >> 3, s = tid & 7;        // 32 channels x 8 slot-pairs
        int c = d0 + d;
        double2 p0 = part[(size_t)c * 16 + s];
        double2 p1 = part[(size_t)c * 16 + s + 8];
        double sum = p0.x + p1.x, sq = p0.y + p1.y;
        sum += __shfl_xor(sum, 4); sq += __shfl_xor(sq, 4);
        sum += __shfl_xor(sum, 2); sq += __shfl_xor(sq, 2);
        sum += __shfl_xor(sum, 1); sq += __shfl_xor(sq, 1);
        if (s == 0) {
            double m = sum * invN;
            double v = sq * invN - m * m;
            double sc = (double)g[c] / sqrt(v + 1e-5);
            sSS[d] = make_float2((float)sc, (float)((double)bb[c] - m * sc));
        }
    }
    __syncthreads();
    const float* hb = h6 + ((size_t)b * 256 + d0) * 4096 + n0;
#pragma unroll
    for (int r = 0; r < 4; r++) {
        int d = ty + 8 * r;
        float2 t = sSS[d];
        sT[d][tx] = lrelu(t.x * hb[d * 4096 + tx] + t.y);
    }
    __syncthreads();
    float* tb = tok + ((size_t)b * 4096 + n0) * 256 + d0;
#pragma unroll
    for (int r = 0; r < 4; r++) {
        int n = ty + 8 * r;
        tb[n * 256 + tx] = sT[tx][n];
    }
}

// ---------------------------------------------------------------------------
// Token stage: gating argmax, selected-expert body slice, ortho, cls MLP.
// ---------------------------------------------------------------------------
__global__ __launch_bounds__(256) void token_k(const float* __restrict__ tok,
                                               const float* __restrict__ wg,
                                               const float* __restrict__ bw,
                                               const float* __restrict__ bb,
                                               const float* __restrict__ ow,
                                               const float* __restrict__ w1,
                                               const float* __restrict__ b1,
                                               const float* __restrict__ w2,
                                               const float* __restrict__ b2,
                                               float* __restrict__ outp) {
    __shared__ float sf[4][256];
    const int tid = threadIdx.x, wave = tid >> 6, l = tid & 63;
    const int t = blockIdx.x * 4 + wave;
    const float4 tv = reinterpret_cast<const float4*>(tok + (size_t)t * 256)[l];
    sf[wave][4 * l + 0] = tv.x; sf[wave][4 * l + 1] = tv.y;
    sf[wave][4 * l + 2] = tv.z; sf[wave][4 * l + 3] = tv.w;

    float lg[12];
#pragma unroll
    for (int e = 0; e < 12; e++) lg[e] = 0.f;
    const float tj[4] = {tv.x, tv.y, tv.z, tv.w};
#pragma unroll
    for (int j = 0; j < 4; j++) {
        const float* wr = wg + (4 * l + j) * 12;
#pragma unroll
        for (int e = 0; e < 12; e++) lg[e] += tj[j] * wr[e];
    }
#pragma unroll
    for (int off = 32; off > 0; off >>= 1) {
#pragma unroll
        for (int e = 0; e < 12; e++) lg[e] += __shfl_xor(lg[e], off);
    }
    int idx = 0; float best = lg[0];
#pragma unroll
    for (int e = 1; e < 12; e++)
        if (lg[e] > best) { best = lg[e]; idx = e; }
    const int cb = idx * 256;

    float f0 = 0.f, f1 = 0.f, f2 = 0.f, f3 = 0.f;
    const float* bwp = bw + cb + 4 * l;
#pragma unroll 4
    for (int d = 0; d < 256; d++) {
        const float td = sf[wave][d];
        const float4 wv = *reinterpret_cast<const float4*>(bwp + (size_t)d * 3072);
        f0 += td * wv.x; f1 += td * wv.y;
        f2 += td * wv.z; f3 += td * wv.w;
    }
    float fj[4] = {f0, f1, f2, f3};
#pragma unroll
    for (int j = 0; j < 4; j++) {
        int jj = cb + 4 * l + j;
        float v = lrelu(fj[j] + bb[jj]);
        v = lrelu(v * ow[jj]);
        sf[wave][4 * l + j] = v;
    }

    float o = 0.f;
    if (l < 32) {
        float h = b1[l];
#pragma unroll 4
        for (int j = 0; j < 256; j++) h += sf[wave][j] * w1[j * 32 + l];
        h = lrelu(h);
        o = h * w2[l];
    }
    o += __shfl_xor(o, 16); o += __shfl_xor(o, 8); o += __shfl_xor(o, 4);
    o += __shfl_xor(o, 2);  o += __shfl_xor(o, 1);
    if (l == 0) outp[t] = o + b2[0];
}

// ---------------------------------------------------------------------------
extern "C" void kernel_launch(void* const* d_in, const int* in_sizes, int n_in,
                              void* d_out, int out_size, void* d_ws, size_t ws_size,
                              hipStream_t stream) {
    const float* x   = (const float*)d_in[0];
    const float* w0  = (const float*)d_in[1];
    const float* b0  = (const float*)d_in[2];
    const float* w1  = (const float*)d_in[3];
    const float* g1  = (const float*)d_in[4];
    const float* be1 = (const float*)d_in[5];
    const float* w2  = (const float*)d_in[6];
    const float* g2  = (const float*)d_in[7];
    const float* be2 = (const float*)d_in[8];
    const float* w3  = (const float*)d_in[9];
    const float* g3  = (const float*)d_in[10];
    const float* be3 = (const float*)d_in[11];
    const float* w4  = (const float*)d_in[12];
    const float* g4  = (const float*)d_in[13];
    const float* be4 = (const float*)d_in[14];
    const float* w5  = (const float*)d_in[15];
    const float* g5  = (const float*)d_in[16];
    const float* be5 = (const float*)d_in[17];
    const float* w6  = (const float*)d_in[18];
    const float* g6  = (const float*)d_in[19];
    const float* be6 = (const float*)d_in[20];
    const float* wg  = (const float*)d_in[21];
    const float* bw  = (const float*)d_in[22];
    const float* bbp = (const float*)d_in[23];
    const float* owp = (const float*)d_in[24];
    const float* cw1 = (const float*)d_in[25];
    const float* cb1 = (const float*)d_in[26];
    const float* cw2 = (const float*)d_in[27];
    const float* cb2 = (const float*)d_in[28];

    char* W = (char*)d_ws;
    double2* part = (double2*)(W + 16384);    // up to 256 KiB of partials

    // Big region @278528 — R1-proven buffer plan (span 105.71 MB).
    char* BIG = W + 278528;
    float* h0p = (float*)(BIG);               // (4,64,258,260) 68.69 MB
    float* h1p = (float*)(BIG + 70287360);    // (8,64,130,132) 35.14 MB
    float* h2p = (float*)(BIG);               // (8,128,130,132) 70.29 MB
    float* h3p = (float*)(BIG + 70287360);    // (8,128,66,68) 18.4 MB
    float* h4p = (float*)(BIG);               // (8,256,66,68) 36.77 MB
    float* h5p = (float*)(BIG + 36765696);    // (8,256,66,68)
    float* h6  = (float*)(BIG);               // (8,256,64,64) 32 MiB
    float* tok = (float*)(BIG + 36765696);    // (8,4096,256) 32 MiB

    // zero h0p borders once (conv0 halves only write interior)
    bnact_k<<<256, 256, 0, stream>>>(h0p, nullptr, 0, 0.0, nullptr, nullptr,
                                     64, 256, 256, 258, 260);
    // conv0 (padded out) + conv1 per half
    for (int half = 0; half < 2; half++) {
        conv0_k<<<dim3(64, 4, 4), 256, 0, stream>>>(
            x + (size_t)half * 4 * 3 * 65536, w0, b0, h0p);
        c4x4p_k<8><<<dim3(16, 4, 8), 256, 0, stream>>>(
            h0p, w1, h1p + (size_t)half * 4 * 64 * 17160, part, half * 64, 128,
            64, 64, 256, 258, 260, 130, 132, 1);
    }
    // bnact h1p with fused BN1 finalize (S=128)
    bnact_k<<<512, 256, 0, stream>>>(h1p, part, 128, 1.0 / 131072.0, g1, be1,
                                     64, 128, 128, 130, 132);
    // conv2 3x3 (tiles 32x64, 2-buffer sync), stats S=64
    c3x3_k<8, false><<<dim3(8, 8, 16), 256, 0, stream>>>(
        h1p, w2, h2p, part, 0, 64, 64, 128, 128, 130, 132, 130, 132, 1);
    bnact_k<<<1024, 256, 0, stream>>>(h2p, part, 64, 1.0 / 131072.0, g2, be2,
                                      128, 128, 128, 130, 132);
    // conv3 4x4 s2, fused stats (S=32)
    c4x4p_k<8><<<dim3(4, 8, 16), 256, 0, stream>>>(
        h2p, w3, h3p, part, 0, 32, 128, 128, 128, 130, 132, 66, 68, 1);
    bnact_k<<<1024, 256, 0, stream>>>(h3p, part, 32, 1.0 / 32768.0, g3, be3,
                                      128, 64, 64, 66, 68);
    // conv4 3x3 (32x64 tiles, PIPELINED), S=16
    c3x3_k<8, true><<<dim3(2, 8, 32), 256, 0, stream>>>(
        h3p, w4, h4p, part, 0, 16, 128, 256, 64, 66, 68, 66, 68, 1);
    bnact_k<<<2048, 256, 0, stream>>>(h4p, part, 16, 1.0 / 32768.0, g4, be4,
                                      256, 64, 64, 66, 68);
    // conv5 3x3: h4p -> h5p, PIPELINED
    c3x3_k<8, true><<<dim3(2, 8, 32), 256, 0, stream>>>(
        h4p, w5, h5p, part, 0, 16, 256, 256, 64, 66, 68, 66, 68, 1);
    bnact_k<<<2048, 256, 0, stream>>>(h5p, part, 16, 1.0 / 32768.0, g5, be5,
                                      256, 64, 64, 66, 68);
    // conv6 3x3: h5p -> h6 unpadded, PIPELINED
    c3x3_k<8, true><<<dim3(2, 8, 32), 256, 0, stream>>>(
        h5p, w6, h6, part, 0, 16, 256, 256, 64, 66, 68, 64, 64, 0);
    // transpose + fused BN6 finalize + lrelu -> tok
    transp_k<<<dim3(128, 8, 8), 256, 0, stream>>>(h6, part, 1.0 / 32768.0,
                                                  g6, be6, tok);
    // token stage -> out fp32 (8,4096,1)
    token_k<<<8192, 256, 0, stream>>>(tok, wg, bw, bbp, owp, cw1, cb1, cw2, cb2,
                                      (float*)d_out);
}

// Round 13
// 2482.866 us; speedup vs baseline: 1.0688x; 1.0222x over previous
//
#include <hip/hip_runtime.h>

__device__ __forceinline__ float lrelu(float x) { return x >= 0.f ? x : 0.2f * x; }

typedef const __attribute__((address_space(1))) void* gas_ptr;
typedef __attribute__((address_space(3))) void* las_ptr;

// ---------------------------------------------------------------------------
// conv0: fp32 x (4,3,256,256) (half batch), w (64,3,3,3), s1 p1, +bias+lrelu
// -> ACTIVATED fp32 PADDED h0p (4,64,258,260), interior at (1,1)
// ---------------------------------------------------------------------------
__global__ __launch_bounds__(256) void conv0_k(const float* __restrict__ x,
                                               const float* __restrict__ w,
                                               const float* __restrict__ bias,
                                               float* __restrict__ out) {
    __shared__ float sIn[3][34][34];
    __shared__ float sW[27][16];
    const int H = 256;
    int tid = threadIdx.x, tx = tid & 31, ty = tid >> 5;
    int tX = (blockIdx.x & 7) * 32, tY = (blockIdx.x >> 3) * 32;
    int b = blockIdx.y, cog = blockIdx.z * 16;
    float acc[4][16] = {};
    const float* inB = x + (size_t)b * 3 * H * H;
    for (int idx = tid; idx < 3 * 1156; idx += 256) {
        int ci = idx / 1156, r = idx % 1156, iy = r / 34, ix = r % 34;
        int gy = tY - 1 + iy, gx = tX - 1 + ix;
        float v = 0.f;
        if ((unsigned)gy < 256u && (unsigned)gx < 256u)
            v = inB[(ci * H + gy) * H + gx];
        sIn[ci][iy][ix] = v;
    }
    for (int idx = tid; idx < 27 * 16; idx += 256) {
        int co = idx & 15, rest = idx >> 4;
        sW[rest][co] = w[(cog + co) * 27 + rest];
    }
    __syncthreads();
#pragma unroll
    for (int ci = 0; ci < 3; ci++)
#pragma unroll
        for (int dy = 0; dy < 3; dy++)
#pragma unroll
            for (int dx = 0; dx < 3; dx++) {
                float a0 = sIn[ci][ty + dy][tx + dx];
                float a1 = sIn[ci][ty + 8 + dy][tx + dx];
                float a2 = sIn[ci][ty + 16 + dy][tx + dx];
                float a3 = sIn[ci][ty + 24 + dy][tx + dx];
                const float* wp = sW[ci * 9 + dy * 3 + dx];
#pragma unroll
                for (int co = 0; co < 16; co++) {
                    float wv = wp[co];
                    acc[0][co] += a0 * wv; acc[1][co] += a1 * wv;
                    acc[2][co] += a2 * wv; acc[3][co] += a3 * wv;
                }
            }
    float* outB = out + (size_t)(b * 64 + cog) * 67080;   // 258*260
#pragma unroll
    for (int co = 0; co < 16; co++) {
        float bv = bias[cog + co];
#pragma unroll
        for (int r = 0; r < 4; r++)
            outB[(size_t)co * 67080 + (size_t)(tY + ty + 8 * r + 1) * 260 +
                 tX + tx + 1] = lrelu(acc[r][co] + bv);
    }
}

// ---------------------------------------------------------------------------
// Shuffle-based BN-stats epilogue for NWV-wave blocks.
// ---------------------------------------------------------------------------
template <int COG, int RPT, int NWV>
__device__ __forceinline__ void stats_epi(float (&acc)[RPT][COG], float2* sRed,
                                          double2* part, int cog, int slotBase,
                                          int S, int tid) {
    const int lane = tid & 63, wv = tid >> 6;
    float s[COG], q[COG];
#pragma unroll
    for (int c = 0; c < COG; c++) {
        float ss = 0.f, qq = 0.f;
#pragma unroll
        for (int j = 0; j < RPT; j++) { float v = acc[j][c]; ss += v; qq += v * v; }
        s[c] = ss; q[c] = qq;
    }
#pragma unroll
    for (int off = 32; off; off >>= 1)
#pragma unroll
        for (int c = 0; c < COG; c++) {
            s[c] += __shfl_xor(s[c], off);
            q[c] += __shfl_xor(q[c], off);
        }
    if (lane == 0)
#pragma unroll
        for (int c = 0; c < COG; c++) sRed[wv * COG + c] = make_float2(s[c], q[c]);
    __syncthreads();
    if (tid < COG) {
        double ss = 0.0, qq = 0.0;
#pragma unroll
        for (int wvi = 0; wvi < NWV; wvi++) {
            float2 p = sRed[wvi * COG + tid];
            ss += (double)p.x; qq += (double)p.y;
        }
        int slot = slotBase + blockIdx.y * gridDim.x + blockIdx.x;
        part[(size_t)(cog + tid) * S + slot] = make_double2(ss, qq);
    }
}

// ---------------------------------------------------------------------------
// 4x4 s2 conv (conv1, conv3): R8 structure verbatim (256 thr, 32x32 tile,
// LDS weight staging, 2-buffer global_load_lds, __syncthreads).
// ---------------------------------------------------------------------------
template <int COG>
__global__ __launch_bounds__(256) void c4x4p_k(const float* __restrict__ in,
                                               const float* __restrict__ w,
                                               float* __restrict__ out,
                                               double2* __restrict__ part,
                                               int slotBase, int S,
                                               int Cin, int Cout, int Hin,
                                               int Hp, int Wp,
                                               int oHp, int oWp, int oOff) {
    __shared__ float sIn[2][4488];            // 66 rows x 68 cols
    __shared__ float sW[2][16 * COG];
    __shared__ float2 sRed[4 * COG];
    const int Hout = Hin >> 1;
    const int tid = threadIdx.x, tx = tid & 31, ty = tid >> 5;
    const int tpr = Hout >> 5;
    const int tX = (blockIdx.x % tpr) * 32, tY = (blockIdx.x / tpr) * 32;
    const int b = blockIdx.y, cog = blockIdx.z * COG;
    const int HWin = Hp * Wp;
    const float* inB = in + (size_t)b * Cin * HWin;
    const int wvbase = tid & ~63;

    int gOff[5]; int lOff[5]; bool act[5];
#pragma unroll
    for (int r = 0; r < 5; r++) {
        int idx = tid + r * 256;
        bool a = idx < 1122;                  // 66 rows x 17 float4
        int row = idx / 17, c4 = idx % 17;
        gOff[r] = a ? ((2 * tY + row) * Wp + 2 * tX + 4 * c4) : 0;
        lOff[r] = (r * 256 + wvbase) * 4;
        act[r] = a;
    }
    const int wco = tid % COG, wt = tid / COG;
    const int wgo = ((cog + wco) * Cin) * 16 + wt;
    const bool wact = tid < 16 * COG;

    float acc[4][COG];
#pragma unroll
    for (int j = 0; j < 4; j++)
#pragma unroll
        for (int c = 0; c < COG; c++) acc[j][c] = 0.f;

#pragma unroll
    for (int r = 0; r < 5; r++)
        if (act[r])
            __builtin_amdgcn_global_load_lds((gas_ptr)(inB + gOff[r]),
                                             (las_ptr)(&sIn[0][lOff[r]]), 16, 0, 0);
    if (wact)
        __builtin_amdgcn_global_load_lds((gas_ptr)(w + wgo),
                                         (las_ptr)(&sW[0][wvbase]), 4, 0, 0);
    __syncthreads();

    for (int k = 0; k < Cin; k++) {
        const int cur = k & 1, nb = cur ^ 1;
        const bool more = (k + 1) < Cin;
        if (more) {
            const float* p = inB + (size_t)(k + 1) * HWin;
#pragma unroll
            for (int r = 0; r < 5; r++)
                if (act[r])
                    __builtin_amdgcn_global_load_lds(
                        (gas_ptr)(p + gOff[r]),
                        (las_ptr)(&sIn[nb][lOff[r]]), 16, 0, 0);
            if (wact)
                __builtin_amdgcn_global_load_lds(
                    (gas_ptr)(w + wgo + (k + 1) * 16),
                    (las_ptr)(&sW[nb][wvbase]), 4, 0, 0);
        }
        const float* sI = sIn[cur];
        const float* sw = sW[cur];
#pragma unroll
        for (int dy = 0; dy < 4; dy++)
#pragma unroll
            for (int dx = 0; dx < 4; dx++) {
                const float* bp = sI + (2 * ty + dy) * 68 + 2 * tx + dx;
                float a0 = bp[0];
                float a1 = bp[16 * 68];
                float a2 = bp[32 * 68];
                float a3 = bp[48 * 68];
                const float* wp = sw + (dy * 4 + dx) * COG;
#pragma unroll
                for (int c = 0; c < COG; c++) {
                    float wv = wp[c];
                    acc[0][c] += a0 * wv; acc[1][c] += a1 * wv;
                    acc[2][c] += a2 * wv; acc[3][c] += a3 * wv;
                }
            }
        __syncthreads();
    }

    float* outB = out + (size_t)(b * Cout + cog) * oHp * oWp;
#pragma unroll
    for (int c = 0; c < COG; c++)
#pragma unroll
        for (int r = 0; r < 4; r++)
            outB[(size_t)c * oHp * oWp +
                 (size_t)(tY + ty + 8 * r + oOff) * oWp + tX + tx + oOff] =
                acc[r][c];
    stats_epi<COG, 4, 4>(acc, sRed, part, cog, slotBase, S, tid);
}

// ---------------------------------------------------------------------------
// 3x3 s1 conv, 256 thr, 32 wide x 64 tall tile, 8 out rows/thread
// (R8 2-buffer path, used for conv2 where 4 blocks/CU fit).
// ---------------------------------------------------------------------------
template <int COG>
__global__ __launch_bounds__(256) void c3x3_k(const float* __restrict__ in,
                                              const float* __restrict__ w,
                                              float* __restrict__ out,
                                              double2* __restrict__ part,
                                              int slotBase, int S,
                                              int Cin, int Cout, int H,
                                              int Hp, int Wp,
                                              int oHp, int oWp, int oOff) {
    constexpr int RS = 36;
    constexpr int ROWS = 66;                  // 64 out rows + 2 halo
    constexpr int CI = ROWS * RS;             // 2376
    constexpr int NSF4 = 2 * ROWS * 9;        // 1188 float4 per 2-cin step
    constexpr int NR = 5;
    __shared__ float sIn[2][2 * CI];
    __shared__ float sW[2][18 * COG];
    __shared__ float2 sRed[4 * COG];
    const int tid = threadIdx.x, tx = tid & 31, ty = tid >> 5;
    const int tpr = H >> 5;                   // x tiles (width 32)
    const int tX = (blockIdx.x % tpr) * 32, tY = (blockIdx.x / tpr) * 64;
    const int b = blockIdx.y, cog = blockIdx.z * COG;
    const int HWin = Hp * Wp;
    const float* inB = in + (size_t)b * Cin * HWin;
    const int wvbase = tid & ~63;

    int gOff[NR]; int lOff[NR]; bool act[NR];
#pragma unroll
    for (int r = 0; r < NR; r++) {
        int idx = tid + r * 256;
        act[r] = idx < NSF4;
        int ci = idx / (9 * ROWS), rem = idx % (9 * ROWS);
        int row = rem / 9, c4 = rem % 9;
        gOff[r] = act[r] ? (ci * HWin + (tY + row) * Wp + tX + 4 * c4) : 0;
        lOff[r] = (r * 256 + wvbase) * 4;
    }
    const bool wact = tid < 18 * COG;
    int wgo;
    {
        int co = tid % COG, rest = tid / COG;
        int ci = rest / 9, t = rest % 9;
        wgo = ((cog + co) * Cin + ci) * 9 + t;
    }

    float acc[8][COG];
#pragma unroll
    for (int j = 0; j < 8; j++)
#pragma unroll
        for (int c = 0; c < COG; c++) acc[j][c] = 0.f;

    const int steps = Cin >> 1;

    auto STAGE = [&](int t, int buf) {
        const float* p = inB + (size_t)(2 * t) * HWin;
#pragma unroll
        for (int r = 0; r < NR; r++)
            if (act[r])
                __builtin_amdgcn_global_load_lds(
                    (gas_ptr)(p + gOff[r]),
                    (las_ptr)(&sIn[buf][lOff[r]]), 16, 0, 0);
        if (wact)
            __builtin_amdgcn_global_load_lds(
                (gas_ptr)(w + (size_t)(2 * t) * 9 + wgo),
                (las_ptr)(&sW[buf][wvbase]), 4, 0, 0);
    };

    STAGE(0, 0);
    __syncthreads();
    for (int k = 0; k < steps; k++) {
        const int cur = k & 1, nb = cur ^ 1;
        if (k + 1 < steps) STAGE(k + 1, nb);
        const float* sI = sIn[cur];
        const float* sw = sW[cur];
#pragma unroll
        for (int ci = 0; ci < 2; ci++)
#pragma unroll
            for (int dx = 0; dx < 3; dx++) {
                const float* bp = sI + ci * CI + (8 * ty) * RS + tx + dx;
                float a[10];
#pragma unroll
                for (int j = 0; j < 10; j++) a[j] = bp[j * RS];
#pragma unroll
                for (int dy = 0; dy < 3; dy++) {
                    const float* wp = sw + (ci * 9 + dy * 3 + dx) * COG;
#pragma unroll
                    for (int c = 0; c < COG; c++) {
                        float wv = wp[c];
#pragma unroll
                        for (int j = 0; j < 8; j++)
                            acc[j][c] += a[j + dy] * wv;
                    }
                }
            }
        __syncthreads();
    }

    float* outB = out + (size_t)(b * Cout + cog) * oHp * oWp;
#pragma unroll
    for (int c = 0; c < COG; c++)
#pragma unroll
        for (int j = 0; j < 8; j++)
            outB[(size_t)c * oHp * oWp +
                 (size_t)(tY + 8 * ty + j + oOff) * oWp + tX + tx + oOff] =
                acc[j][c];
    stats_epi<COG, 8, 4>(acc, sRed, part, cog, slotBase, S, tid);
}

// ---------------------------------------------------------------------------
// 3x3 s1 conv, 128 thr, 32x32 tile, 8 out rows/thread (R9 version —
// measured 471 us on conv5/6: 4 independent 2-wave barrier groups/CU).
// Used for conv4/5/6.
// ---------------------------------------------------------------------------
template <int COG>
__global__ __launch_bounds__(128) void c3x3h_k(const float* __restrict__ in,
                                               const float* __restrict__ w,
                                               float* __restrict__ out,
                                               double2* __restrict__ part,
                                               int slotBase, int S,
                                               int Cin, int Cout, int H,
                                               int Hp, int Wp,
                                               int oHp, int oWp, int oOff) {
    constexpr int RS = 36;
    constexpr int ROWS = 34;                  // 32 out rows + 2 halo
    constexpr int CI = ROWS * RS;             // 1224
    constexpr int NSF4 = 2 * ROWS * 9;        // 612 float4 per 2-cin step
    constexpr int NR = (NSF4 + 127) / 128;    // 5
    constexpr int NWR = (18 * COG + 127) / 128;  // 2
    __shared__ float sIn[2][2 * CI];
    __shared__ float sW[2][18 * COG];
    __shared__ float2 sRed[2 * COG];
    const int tid = threadIdx.x, tx = tid & 31, ty = tid >> 5;   // ty 0..3
    const int tpr = H >> 5;                   // x tiles (32 wide)
    const int tX = (blockIdx.x % tpr) * 32, tY = (blockIdx.x / tpr) * 32;
    const int b = blockIdx.y, cog = blockIdx.z * COG;
    const int HWin = Hp * Wp;
    const float* inB = in + (size_t)b * Cin * HWin;
    const int wvbase = tid & ~63;

    int gOff[NR]; int lOff[NR]; bool act[NR];
#pragma unroll
    for (int r = 0; r < NR; r++) {
        int idx = tid + r * 128;
        bool a = idx < NSF4;
        int ci = idx / (9 * ROWS), rem = idx % (9 * ROWS);
        int row = rem / 9, c4 = rem % 9;
        gOff[r] = a ? (ci * HWin + (tY + row) * Wp + tX + 4 * c4) : 0;
        lOff[r] = (r * 128 + wvbase) * 4;
        act[r] = a;
    }
    int wgo[NWR]; bool wact[NWR]; int wlo[NWR];
#pragma unroll
    for (int r = 0; r < NWR; r++) {
        int widx = tid + r * 128;
        bool a = widx < 18 * COG;
        int co = widx % COG, rest = widx / COG;
        int ci = rest / 9, t = rest % 9;
        wgo[r] = a ? (((cog + co) * Cin + ci) * 9 + t) : 0;
        wlo[r] = r * 128 + wvbase;
        wact[r] = a;
    }

    float acc[8][COG];
#pragma unroll
    for (int j = 0; j < 8; j++)
#pragma unroll
        for (int c = 0; c < COG; c++) acc[j][c] = 0.f;

    const int steps = Cin >> 1;

    auto STAGE = [&](int t, int buf) {
        const float* p = inB + (size_t)(2 * t) * HWin;
#pragma unroll
        for (int r = 0; r < NR; r++)
            if (act[r])
                __builtin_amdgcn_global_load_lds(
                    (gas_ptr)(p + gOff[r]),
                    (las_ptr)(&sIn[buf][lOff[r]]), 16, 0, 0);
        const float* wp2 = w + (size_t)(2 * t) * 9;
#pragma unroll
        for (int r = 0; r < NWR; r++)
            if (wact[r])
                __builtin_amdgcn_global_load_lds(
                    (gas_ptr)(wp2 + wgo[r]),
                    (las_ptr)(&sW[buf][wlo[r]]), 4, 0, 0);
    };

    STAGE(0, 0);
    __syncthreads();
    for (int k = 0; k < steps; k++) {
        const int cur = k & 1, nb = cur ^ 1;
        if (k + 1 < steps) STAGE(k + 1, nb);
        const float* sI = sIn[cur];
        const float* sw = sW[cur];
#pragma unroll
        for (int ci = 0; ci < 2; ci++)
#pragma unroll
            for (int dx = 0; dx < 3; dx++) {
                const float* bp = sI + ci * CI + (8 * ty) * RS + tx + dx;
                float a[10];
#pragma unroll
                for (int j = 0; j < 10; j++) a[j] = bp[j * RS];
#pragma unroll
                for (int dy = 0; dy < 3; dy++) {
                    const float* wp = sw + (ci * 9 + dy * 3 + dx) * COG;
#pragma unroll
                    for (int c = 0; c < COG; c++) {
                        float wv = wp[c];
#pragma unroll
                        for (int j = 0; j < 8; j++)
                            acc[j][c] += a[j + dy] * wv;
                    }
                }
            }
        __syncthreads();
    }

    float* outB = out + (size_t)(b * Cout + cog) * oHp * oWp;
#pragma unroll
    for (int c = 0; c < COG; c++)
#pragma unroll
        for (int j = 0; j < 8; j++)
            outB[(size_t)c * oHp * oWp +
                 (size_t)(tY + 8 * ty + j + oOff) * oWp + tX + tx + oOff] =
                acc[j][c];
    stats_epi<COG, 8, 2>(acc, sRed, part, cog, slotBase, S, tid);
}

// ---------------------------------------------------------------------------
// bnact: FUSED bnfin — each block reduces its channel's (sum,sumsq)
// partials in-block, computes (scale, shift), zeroes padded border,
// transforms interior with lrelu(sc*x+sh). part==nullptr -> border only.
// ---------------------------------------------------------------------------
__global__ __launch_bounds__(256) void bnact_k(float* __restrict__ p,
                                               const double2* __restrict__ part,
                                               int S, double invN,
                                               const float* __restrict__ g,
                                               const float* __restrict__ bb,
                                               int C, int H, int W,
                                               int Hp, int Wp) {
    __shared__ double2 red[4];
    __shared__ float2 sSS;
    int pc = blockIdx.x;
    int c = pc & (C - 1);
    int tid = threadIdx.x;
    const bool xf = (part != nullptr);
    if (xf) {
        double sum = 0.0, sq = 0.0;
        for (int s = tid; s < S; s += 256) {
            double2 pp = part[(size_t)c * S + s];
            sum += pp.x; sq += pp.y;
        }
#pragma unroll
        for (int off = 32; off; off >>= 1) {
            sum += __shfl_xor(sum, off);
            sq += __shfl_xor(sq, off);
        }
        if ((tid & 63) == 0) red[tid >> 6] = make_double2(sum, sq);
        __syncthreads();
        if (tid == 0) {
            double s2 = 0.0, q2 = 0.0;
#pragma unroll
            for (int wv = 0; wv < 4; wv++) { s2 += red[wv].x; q2 += red[wv].y; }
            double m = s2 * invN;
            double v = q2 * invN - m * m;
            double sc = (double)g[c] / sqrt(v + 1e-5);
            sSS = make_float2((float)sc, (float)((double)bb[c] - m * sc));
        }
        __syncthreads();
    }
    float2 t = xf ? sSS : make_float2(1.f, 0.f);
    float* pl = p + (size_t)pc * Hp * Wp;
    int n = Hp * Wp;
    for (int i = tid; i < n; i += 256) {
        int y = i / Wp, x = i - y * Wp;
        bool inter = (y >= 1) && (y <= H) && (x >= 1) && (x <= W);
        if (!inter) pl[i] = 0.f;
        else if (xf) { float v = pl[i]; pl[i] = lrelu(t.x * v + t.y); }
    }
}

// ---------------------------------------------------------------------------
// transp: h6 raw (8,256,64,64) + FUSED BN6 finalize (S=32 slots) + lrelu
// -> tok (8,4096,256). Per block: 8 threads/channel reduce 32 slots.
// ---------------------------------------------------------------------------
__global__ __launch_bounds__(256) void transp_k(const float* __restrict__ h6,
                                                const double2* __restrict__ part,
                                                double invN,
                                                const float* __restrict__ g,
                                                const float* __restrict__ bb,
                                                float* __restrict__ tok) {
    __shared__ float sT[32][33];
    __shared__ float2 sSS[32];
    int tid = threadIdx.x;
    int tx = tid & 31, ty = tid >> 5;
    int n0 = blockIdx.x * 32, d0 = blockIdx.y * 32, b = blockIdx.z;
    {
        int d = tid >> 3, s = tid & 7;        // 32 channels x 8 lanes each
        int c = d0 + d;
        double sum = 0.0, sq = 0.0;
#pragma unroll
        for (int i = 0; i < 4; i++) {
            double2 pp = part[(size_t)c * 32 + s + 8 * i];
            sum += pp.x; sq += pp.y;
        }
        sum += __shfl_xor(sum, 4); sq += __shfl_xor(sq, 4);
        sum += __shfl_xor(sum, 2); sq += __shfl_xor(sq, 2);
        sum += __shfl_xor(sum, 1); sq += __shfl_xor(sq, 1);
        if (s == 0) {
            double m = sum * invN;
            double v = sq * invN - m * m;
            double sc = (double)g[c] / sqrt(v + 1e-5);
            sSS[d] = make_float2((float)sc, (float)((double)bb[c] - m * sc));
        }
    }
    __syncthreads();
    const float* hb = h6 + ((size_t)b * 256 + d0) * 4096 + n0;
#pragma unroll
    for (int r = 0; r < 4; r++) {
        int d = ty + 8 * r;
        float2 t = sSS[d];
        sT[d][tx] = lrelu(t.x * hb[d * 4096 + tx] + t.y);
    }
    __syncthreads();
    float* tb = tok + ((size_t)b * 4096 + n0) * 256 + d0;
#pragma unroll
    for (int r = 0; r < 4; r++) {
        int n = ty + 8 * r;
        tb[n * 256 + tx] = sT[tx][n];
    }
}

// ---------------------------------------------------------------------------
// Token stage: gating argmax, selected-expert body slice, ortho, cls MLP.
// ---------------------------------------------------------------------------
__global__ __launch_bounds__(256) void token_k(const float* __restrict__ tok,
                                               const float* __restrict__ wg,
                                               const float* __restrict__ bw,
                                               const float* __restrict__ bb,
                                               const float* __restrict__ ow,
                                               const float* __restrict__ w1,
                                               const float* __restrict__ b1,
                                               const float* __restrict__ w2,
                                               const float* __restrict__ b2,
                                               float* __restrict__ outp) {
    __shared__ float sf[4][256];
    const int tid = threadIdx.x, wave = tid >> 6, l = tid & 63;
    const int t = blockIdx.x * 4 + wave;
    const float4 tv = reinterpret_cast<const float4*>(tok + (size_t)t * 256)[l];
    sf[wave][4 * l + 0] = tv.x; sf[wave][4 * l + 1] = tv.y;
    sf[wave][4 * l + 2] = tv.z; sf[wave][4 * l + 3] = tv.w;

    float lg[12];
#pragma unroll
    for (int e = 0; e < 12; e++) lg[e] = 0.f;
    const float tj[4] = {tv.x, tv.y, tv.z, tv.w};
#pragma unroll
    for (int j = 0; j < 4; j++) {
        const float* wr = wg + (4 * l + j) * 12;
#pragma unroll
        for (int e = 0; e < 12; e++) lg[e] += tj[j] * wr[e];
    }
#pragma unroll
    for (int off = 32; off > 0; off >>= 1) {
#pragma unroll
        for (int e = 0; e < 12; e++) lg[e] += __shfl_xor(lg[e], off);
    }
    int idx = 0; float best = lg[0];
#pragma unroll
    for (int e = 1; e < 12; e++)
        if (lg[e] > best) { best = lg[e]; idx = e; }
    const int cb = idx * 256;

    float f0 = 0.f, f1 = 0.f, f2 = 0.f, f3 = 0.f;
    const float* bwp = bw + cb + 4 * l;
#pragma unroll 4
    for (int d = 0; d < 256; d++) {
        const float td = sf[wave][d];
        const float4 wv = *reinterpret_cast<const float4*>(bwp + (size_t)d * 3072);
        f0 += td * wv.x; f1 += td * wv.y;
        f2 += td * wv.z; f3 += td * wv.w;
    }
    float fj[4] = {f0, f1, f2, f3};
#pragma unroll
    for (int j = 0; j < 4; j++) {
        int jj = cb + 4 * l + j;
        float v = lrelu(fj[j] + bb[jj]);
        v = lrelu(v * ow[jj]);
        sf[wave][4 * l + j] = v;
    }

    float o = 0.f;
    if (l < 32) {
        float h = b1[l];
#pragma unroll 4
        for (int j = 0; j < 256; j++) h += sf[wave][j] * w1[j * 32 + l];
        h = lrelu(h);
        o = h * w2[l];
    }
    o += __shfl_xor(o, 16); o += __shfl_xor(o, 8); o += __shfl_xor(o, 4);
    o += __shfl_xor(o, 2);  o += __shfl_xor(o, 1);
    if (l == 0) outp[t] = o + b2[0];
}

// ---------------------------------------------------------------------------
extern "C" void kernel_launch(void* const* d_in, const int* in_sizes, int n_in,
                              void* d_out, int out_size, void* d_ws, size_t ws_size,
                              hipStream_t stream) {
    const float* x   = (const float*)d_in[0];
    const float* w0  = (const float*)d_in[1];
    const float* b0  = (const float*)d_in[2];
    const float* w1  = (const float*)d_in[3];
    const float* g1  = (const float*)d_in[4];
    const float* be1 = (const float*)d_in[5];
    const float* w2  = (const float*)d_in[6];
    const float* g2  = (const float*)d_in[7];
    const float* be2 = (const float*)d_in[8];
    const float* w3  = (const float*)d_in[9];
    const float* g3  = (const float*)d_in[10];
    const float* be3 = (const float*)d_in[11];
    const float* w4  = (const float*)d_in[12];
    const float* g4  = (const float*)d_in[13];
    const float* be4 = (const float*)d_in[14];
    const float* w5  = (const float*)d_in[15];
    const float* g5  = (const float*)d_in[16];
    const float* be5 = (const float*)d_in[17];
    const float* w6  = (const float*)d_in[18];
    const float* g6  = (const float*)d_in[19];
    const float* be6 = (const float*)d_in[20];
    const float* wg  = (const float*)d_in[21];
    const float* bw  = (const float*)d_in[22];
    const float* bbp = (const float*)d_in[23];
    const float* owp = (const float*)d_in[24];
    const float* cw1 = (const float*)d_in[25];
    const float* cb1 = (const float*)d_in[26];
    const float* cw2 = (const float*)d_in[27];
    const float* cb2 = (const float*)d_in[28];

    char* W = (char*)d_ws;
    double2* part = (double2*)(W + 16384);    // up to 256 KiB of partials

    // Big region @278528 — R1-proven buffer plan (span 105.71 MB).
    char* BIG = W + 278528;
    float* h0p = (float*)(BIG);               // (4,64,258,260) 68.69 MB
    float* h1p = (float*)(BIG + 70287360);    // (8,64,130,132) 35.14 MB
    float* h2p = (float*)(BIG);               // (8,128,130,132) 70.29 MB
    float* h3p = (float*)(BIG + 70287360);    // (8,128,66,68) 18.4 MB
    float* h4p = (float*)(BIG);               // (8,256,66,68) 36.77 MB
    float* h5p = (float*)(BIG + 36765696);    // (8,256,66,68)
    float* h6  = (float*)(BIG);               // (8,256,64,64) 32 MiB
    float* tok = (float*)(BIG + 36765696);    // (8,4096,256) 32 MiB

    // zero h0p borders once (conv0 halves only write interior)
    bnact_k<<<256, 256, 0, stream>>>(h0p, nullptr, 0, 0.0, nullptr, nullptr,
                                     64, 256, 256, 258, 260);
    // conv0 (padded out) + conv1 per half
    for (int half = 0; half < 2; half++) {
        conv0_k<<<dim3(64, 4, 4), 256, 0, stream>>>(
            x + (size_t)half * 4 * 3 * 65536, w0, b0, h0p);
        c4x4p_k<8><<<dim3(16, 4, 8), 256, 0, stream>>>(
            h0p, w1, h1p + (size_t)half * 4 * 64 * 17160, part, half * 64, 128,
            64, 64, 256, 258, 260, 130, 132, 1);
    }
    // bnact h1p with fused BN1 finalize (S=128)
    bnact_k<<<512, 256, 0, stream>>>(h1p, part, 128, 1.0 / 131072.0, g1, be1,
                                     64, 128, 128, 130, 132);
    // conv2 3x3 (256 thr, 32x64 tiles): 1024 blocks, stats S=64
    c3x3_k<8><<<dim3(8, 8, 16), 256, 0, stream>>>(
        h1p, w2, h2p, part, 0, 64, 64, 128, 128, 130, 132, 130, 132, 1);
    bnact_k<<<1024, 256, 0, stream>>>(h2p, part, 64, 1.0 / 131072.0, g2, be2,
                                      128, 128, 128, 130, 132);
    // conv3 4x4 s2 (256 thr, 32x32 tiles), stats S=32
    c4x4p_k<8><<<dim3(4, 8, 16), 256, 0, stream>>>(
        h2p, w3, h3p, part, 0, 32, 128, 128, 128, 130, 132, 66, 68, 1);
    bnact_k<<<1024, 256, 0, stream>>>(h3p, part, 32, 1.0 / 32768.0, g3, be3,
                                      128, 64, 64, 66, 68);
    // conv4 3x3 (128 thr, 32x32 tiles): 1024 blocks, stats S=32
    c3x3h_k<8><<<dim3(4, 8, 32), 128, 0, stream>>>(
        h3p, w4, h4p, part, 0, 32, 128, 256, 64, 66, 68, 66, 68, 1);
    bnact_k<<<2048, 256, 0, stream>>>(h4p, part, 32, 1.0 / 32768.0, g4, be4,
                                      256, 64, 64, 66, 68);
    // conv5 3x3 (128 thr): 1024 blocks
    c3x3h_k<8><<<dim3(4, 8, 32), 128, 0, stream>>>(
        h4p, w5, h5p, part, 0, 32, 256, 256, 64, 66, 68, 66, 68, 1);
    bnact_k<<<2048, 256, 0, stream>>>(h5p, part, 32, 1.0 / 32768.0, g5, be5,
                                      256, 64, 64, 66, 68);
    // conv6 3x3 (128 thr): h5p -> h6 unpadded, stats S=32
    c3x3h_k<8><<<dim3(4, 8, 32), 128, 0, stream>>>(
        h5p, w6, h6, part, 0, 32, 256, 256, 64, 66, 68, 64, 64, 0);
    // transpose + fused BN6 finalize (S=32) + lrelu -> tok
    transp_k<<<dim3(128, 8, 8), 256, 0, stream>>>(h6, part, 1.0 / 32768.0,
                                                  g6, be6, tok);
    // token stage -> out fp32 (8,4096,1)
    token_k<<<8192, 256, 0, stream>>>(tok, wg, bw, bbp, owp, cw1, cb1, cw2, cb2,
                                      (float*)d_out);
}

// Round 14
// 2360.468 us; speedup vs baseline: 1.1242x; 1.0519x over previous
//
#include <hip/hip_runtime.h>

__device__ __forceinline__ float lrelu(float x) { return x >= 0.f ? x : 0.2f * x; }

typedef const __attribute__((address_space(1))) void* gas_ptr;
typedef __attribute__((address_space(3))) void* las_ptr;

// ---------------------------------------------------------------------------
// conv0: fp32 x (4,3,256,256) (half batch), w (64,3,3,3), s1 p1, +bias+lrelu
// -> ACTIVATED fp32 PADDED h0p (4,64,258,260), interior at (1,1)
// ---------------------------------------------------------------------------
__global__ __launch_bounds__(256) void conv0_k(const float* __restrict__ x,
                                               const float* __restrict__ w,
                                               const float* __restrict__ bias,
                                               float* __restrict__ out) {
    __shared__ float sIn[3][34][34];
    __shared__ float sW[27][16];
    const int H = 256;
    int tid = threadIdx.x, tx = tid & 31, ty = tid >> 5;
    int tX = (blockIdx.x & 7) * 32, tY = (blockIdx.x >> 3) * 32;
    int b = blockIdx.y, cog = blockIdx.z * 16;
    float acc[4][16] = {};
    const float* inB = x + (size_t)b * 3 * H * H;
    for (int idx = tid; idx < 3 * 1156; idx += 256) {
        int ci = idx / 1156, r = idx % 1156, iy = r / 34, ix = r % 34;
        int gy = tY - 1 + iy, gx = tX - 1 + ix;
        float v = 0.f;
        if ((unsigned)gy < 256u && (unsigned)gx < 256u)
            v = inB[(ci * H + gy) * H + gx];
        sIn[ci][iy][ix] = v;
    }
    for (int idx = tid; idx < 27 * 16; idx += 256) {
        int co = idx & 15, rest = idx >> 4;
        sW[rest][co] = w[(cog + co) * 27 + rest];
    }
    __syncthreads();
#pragma unroll
    for (int ci = 0; ci < 3; ci++)
#pragma unroll
        for (int dy = 0; dy < 3; dy++)
#pragma unroll
            for (int dx = 0; dx < 3; dx++) {
                float a0 = sIn[ci][ty + dy][tx + dx];
                float a1 = sIn[ci][ty + 8 + dy][tx + dx];
                float a2 = sIn[ci][ty + 16 + dy][tx + dx];
                float a3 = sIn[ci][ty + 24 + dy][tx + dx];
                const float* wp = sW[ci * 9 + dy * 3 + dx];
#pragma unroll
                for (int co = 0; co < 16; co++) {
                    float wv = wp[co];
                    acc[0][co] += a0 * wv; acc[1][co] += a1 * wv;
                    acc[2][co] += a2 * wv; acc[3][co] += a3 * wv;
                }
            }
    float* outB = out + (size_t)(b * 64 + cog) * 67080;   // 258*260
#pragma unroll
    for (int co = 0; co < 16; co++) {
        float bv = bias[cog + co];
#pragma unroll
        for (int r = 0; r < 4; r++)
            outB[(size_t)co * 67080 + (size_t)(tY + ty + 8 * r + 1) * 260 +
                 tX + tx + 1] = lrelu(acc[r][co] + bv);
    }
}

// ---------------------------------------------------------------------------
// Shuffle-based BN-stats epilogue for NWV-wave blocks.
// ---------------------------------------------------------------------------
template <int COG, int RPT, int NWV>
__device__ __forceinline__ void stats_epi(float (&acc)[RPT][COG], float2* sRed,
                                          double2* part, int cog, int slotBase,
                                          int S, int tid) {
    const int lane = tid & 63, wv = tid >> 6;
    float s[COG], q[COG];
#pragma unroll
    for (int c = 0; c < COG; c++) {
        float ss = 0.f, qq = 0.f;
#pragma unroll
        for (int j = 0; j < RPT; j++) { float v = acc[j][c]; ss += v; qq += v * v; }
        s[c] = ss; q[c] = qq;
    }
#pragma unroll
    for (int off = 32; off; off >>= 1)
#pragma unroll
        for (int c = 0; c < COG; c++) {
            s[c] += __shfl_xor(s[c], off);
            q[c] += __shfl_xor(q[c], off);
        }
    if (lane == 0)
#pragma unroll
        for (int c = 0; c < COG; c++) sRed[wv * COG + c] = make_float2(s[c], q[c]);
    __syncthreads();
    if (tid < COG) {
        double ss = 0.0, qq = 0.0;
#pragma unroll
        for (int wvi = 0; wvi < NWV; wvi++) {
            float2 p = sRed[wvi * COG + tid];
            ss += (double)p.x; qq += (double)p.y;
        }
        int slot = slotBase + blockIdx.y * gridDim.x + blockIdx.x;
        part[(size_t)(cog + tid) * S + slot] = make_double2(ss, qq);
    }
}

// ---------------------------------------------------------------------------
// 4x4 s2 conv (conv1, conv3): R8 structure verbatim (256 thr, 32x32 tile,
// LDS weight staging, 2-buffer global_load_lds, __syncthreads).
// ---------------------------------------------------------------------------
template <int COG>
__global__ __launch_bounds__(256) void c4x4p_k(const float* __restrict__ in,
                                               const float* __restrict__ w,
                                               float* __restrict__ out,
                                               double2* __restrict__ part,
                                               int slotBase, int S,
                                               int Cin, int Cout, int Hin,
                                               int Hp, int Wp,
                                               int oHp, int oWp, int oOff) {
    __shared__ float sIn[2][4488];            // 66 rows x 68 cols
    __shared__ float sW[2][16 * COG];
    __shared__ float2 sRed[4 * COG];
    const int Hout = Hin >> 1;
    const int tid = threadIdx.x, tx = tid & 31, ty = tid >> 5;
    const int tpr = Hout >> 5;
    const int tX = (blockIdx.x % tpr) * 32, tY = (blockIdx.x / tpr) * 32;
    const int b = blockIdx.y, cog = blockIdx.z * COG;
    const int HWin = Hp * Wp;
    const float* inB = in + (size_t)b * Cin * HWin;
    const int wvbase = tid & ~63;

    int gOff[5]; int lOff[5]; bool act[5];
#pragma unroll
    for (int r = 0; r < 5; r++) {
        int idx = tid + r * 256;
        bool a = idx < 1122;                  // 66 rows x 17 float4
        int row = idx / 17, c4 = idx % 17;
        gOff[r] = a ? ((2 * tY + row) * Wp + 2 * tX + 4 * c4) : 0;
        lOff[r] = (r * 256 + wvbase) * 4;
        act[r] = a;
    }
    const int wco = tid % COG, wt = tid / COG;
    const int wgo = ((cog + wco) * Cin) * 16 + wt;
    const bool wact = tid < 16 * COG;

    float acc[4][COG];
#pragma unroll
    for (int j = 0; j < 4; j++)
#pragma unroll
        for (int c = 0; c < COG; c++) acc[j][c] = 0.f;

#pragma unroll
    for (int r = 0; r < 5; r++)
        if (act[r])
            __builtin_amdgcn_global_load_lds((gas_ptr)(inB + gOff[r]),
                                             (las_ptr)(&sIn[0][lOff[r]]), 16, 0, 0);
    if (wact)
        __builtin_amdgcn_global_load_lds((gas_ptr)(w + wgo),
                                         (las_ptr)(&sW[0][wvbase]), 4, 0, 0);
    __syncthreads();

    for (int k = 0; k < Cin; k++) {
        const int cur = k & 1, nb = cur ^ 1;
        const bool more = (k + 1) < Cin;
        if (more) {
            const float* p = inB + (size_t)(k + 1) * HWin;
#pragma unroll
            for (int r = 0; r < 5; r++)
                if (act[r])
                    __builtin_amdgcn_global_load_lds(
                        (gas_ptr)(p + gOff[r]),
                        (las_ptr)(&sIn[nb][lOff[r]]), 16, 0, 0);
            if (wact)
                __builtin_amdgcn_global_load_lds(
                    (gas_ptr)(w + wgo + (k + 1) * 16),
                    (las_ptr)(&sW[nb][wvbase]), 4, 0, 0);
        }
        const float* sI = sIn[cur];
        const float* sw = sW[cur];
#pragma unroll
        for (int dy = 0; dy < 4; dy++)
#pragma unroll
            for (int dx = 0; dx < 4; dx++) {
                const float* bp = sI + (2 * ty + dy) * 68 + 2 * tx + dx;
                float a0 = bp[0];
                float a1 = bp[16 * 68];
                float a2 = bp[32 * 68];
                float a3 = bp[48 * 68];
                const float* wp = sw + (dy * 4 + dx) * COG;
#pragma unroll
                for (int c = 0; c < COG; c++) {
                    float wv = wp[c];
                    acc[0][c] += a0 * wv; acc[1][c] += a1 * wv;
                    acc[2][c] += a2 * wv; acc[3][c] += a3 * wv;
                }
            }
        __syncthreads();
    }

    float* outB = out + (size_t)(b * Cout + cog) * oHp * oWp;
#pragma unroll
    for (int c = 0; c < COG; c++)
#pragma unroll
        for (int r = 0; r < 4; r++)
            outB[(size_t)c * oHp * oWp +
                 (size_t)(tY + ty + 8 * r + oOff) * oWp + tX + tx + oOff] =
                acc[r][c];
    stats_epi<COG, 4, 4>(acc, sRed, part, cog, slotBase, S, tid);
}

// ---------------------------------------------------------------------------
// 3x3 s1 conv, 256 thr, 32 wide x 64 tall tile, 8 out rows/thread
// (R8 2-buffer path, used for conv2 where 4 blocks/CU fit).
// ---------------------------------------------------------------------------
template <int COG>
__global__ __launch_bounds__(256) void c3x3_k(const float* __restrict__ in,
                                              const float* __restrict__ w,
                                              float* __restrict__ out,
                                              double2* __restrict__ part,
                                              int slotBase, int S,
                                              int Cin, int Cout, int H,
                                              int Hp, int Wp,
                                              int oHp, int oWp, int oOff) {
    constexpr int RS = 36;
    constexpr int ROWS = 66;                  // 64 out rows + 2 halo
    constexpr int CI = ROWS * RS;             // 2376
    constexpr int NSF4 = 2 * ROWS * 9;        // 1188 float4 per 2-cin step
    constexpr int NR = 5;
    __shared__ float sIn[2][2 * CI];
    __shared__ float sW[2][18 * COG];
    __shared__ float2 sRed[4 * COG];
    const int tid = threadIdx.x, tx = tid & 31, ty = tid >> 5;
    const int tpr = H >> 5;                   // x tiles (width 32)
    const int tX = (blockIdx.x % tpr) * 32, tY = (blockIdx.x / tpr) * 64;
    const int b = blockIdx.y, cog = blockIdx.z * COG;
    const int HWin = Hp * Wp;
    const float* inB = in + (size_t)b * Cin * HWin;
    const int wvbase = tid & ~63;

    int gOff[NR]; int lOff[NR]; bool act[NR];
#pragma unroll
    for (int r = 0; r < NR; r++) {
        int idx = tid + r * 256;
        act[r] = idx < NSF4;
        int ci = idx / (9 * ROWS), rem = idx % (9 * ROWS);
        int row = rem / 9, c4 = rem % 9;
        gOff[r] = act[r] ? (ci * HWin + (tY + row) * Wp + tX + 4 * c4) : 0;
        lOff[r] = (r * 256 + wvbase) * 4;
    }
    const bool wact = tid < 18 * COG;
    int wgo;
    {
        int co = tid % COG, rest = tid / COG;
        int ci = rest / 9, t = rest % 9;
        wgo = ((cog + co) * Cin + ci) * 9 + t;
    }

    float acc[8][COG];
#pragma unroll
    for (int j = 0; j < 8; j++)
#pragma unroll
        for (int c = 0; c < COG; c++) acc[j][c] = 0.f;

    const int steps = Cin >> 1;

    auto STAGE = [&](int t, int buf) {
        const float* p = inB + (size_t)(2 * t) * HWin;
#pragma unroll
        for (int r = 0; r < NR; r++)
            if (act[r])
                __builtin_amdgcn_global_load_lds(
                    (gas_ptr)(p + gOff[r]),
                    (las_ptr)(&sIn[buf][lOff[r]]), 16, 0, 0);
        if (wact)
            __builtin_amdgcn_global_load_lds(
                (gas_ptr)(w + (size_t)(2 * t) * 9 + wgo),
                (las_ptr)(&sW[buf][wvbase]), 4, 0, 0);
    };

    STAGE(0, 0);
    __syncthreads();
    for (int k = 0; k < steps; k++) {
        const int cur = k & 1, nb = cur ^ 1;
        if (k + 1 < steps) STAGE(k + 1, nb);
        const float* sI = sIn[cur];
        const float* sw = sW[cur];
#pragma unroll
        for (int ci = 0; ci < 2; ci++)
#pragma unroll
            for (int dx = 0; dx < 3; dx++) {
                const float* bp = sI + ci * CI + (8 * ty) * RS + tx + dx;
                float a[10];
#pragma unroll
                for (int j = 0; j < 10; j++) a[j] = bp[j * RS];
#pragma unroll
                for (int dy = 0; dy < 3; dy++) {
                    const float* wp = sw + (ci * 9 + dy * 3 + dx) * COG;
#pragma unroll
                    for (int c = 0; c < COG; c++) {
                        float wv = wp[c];
#pragma unroll
                        for (int j = 0; j < 8; j++)
                            acc[j][c] += a[j + dy] * wv;
                    }
                }
            }
        __syncthreads();
    }

    float* outB = out + (size_t)(b * Cout + cog) * oHp * oWp;
#pragma unroll
    for (int c = 0; c < COG; c++)
#pragma unroll
        for (int j = 0; j < 8; j++)
            outB[(size_t)c * oHp * oWp +
                 (size_t)(tY + 8 * ty + j + oOff) * oWp + tX + tx + oOff] =
                acc[j][c];
    stats_epi<COG, 8, 4>(acc, sRed, part, cog, slotBase, S, tid);
}

// ---------------------------------------------------------------------------
// 3x3 s1 conv, 128 thr, 32x32 tile, 8 out rows/thread (R9 version —
// 4 independent 2-wave barrier groups/CU). Used for conv4/5/6.
// ---------------------------------------------------------------------------
template <int COG>
__global__ __launch_bounds__(128) void c3x3h_k(const float* __restrict__ in,
                                               const float* __restrict__ w,
                                               float* __restrict__ out,
                                               double2* __restrict__ part,
                                               int slotBase, int S,
                                               int Cin, int Cout, int H,
                                               int Hp, int Wp,
                                               int oHp, int oWp, int oOff) {
    constexpr int RS = 36;
    constexpr int ROWS = 34;                  // 32 out rows + 2 halo
    constexpr int CI = ROWS * RS;             // 1224
    constexpr int NSF4 = 2 * ROWS * 9;        // 612 float4 per 2-cin step
    constexpr int NR = (NSF4 + 127) / 128;    // 5
    constexpr int NWR = (18 * COG + 127) / 128;  // 2
    __shared__ float sIn[2][2 * CI];
    __shared__ float sW[2][18 * COG];
    __shared__ float2 sRed[2 * COG];
    const int tid = threadIdx.x, tx = tid & 31, ty = tid >> 5;   // ty 0..3
    const int tpr = H >> 5;                   // x tiles (32 wide)
    const int tX = (blockIdx.x % tpr) * 32, tY = (blockIdx.x / tpr) * 32;
    const int b = blockIdx.y, cog = blockIdx.z * COG;
    const int HWin = Hp * Wp;
    const float* inB = in + (size_t)b * Cin * HWin;
    const int wvbase = tid & ~63;

    int gOff[NR]; int lOff[NR]; bool act[NR];
#pragma unroll
    for (int r = 0; r < NR; r++) {
        int idx = tid + r * 128;
        bool a = idx < NSF4;
        int ci = idx / (9 * ROWS), rem = idx % (9 * ROWS);
        int row = rem / 9, c4 = rem % 9;
        gOff[r] = a ? (ci * HWin + (tY + row) * Wp + tX + 4 * c4) : 0;
        lOff[r] = (r * 128 + wvbase) * 4;
        act[r] = a;
    }
    int wgo[NWR]; bool wact[NWR]; int wlo[NWR];
#pragma unroll
    for (int r = 0; r < NWR; r++) {
        int widx = tid + r * 128;
        bool a = widx < 18 * COG;
        int co = widx % COG, rest = widx / COG;
        int ci = rest / 9, t = rest % 9;
        wgo[r] = a ? (((cog + co) * Cin + ci) * 9 + t) : 0;
        wlo[r] = r * 128 + wvbase;
        wact[r] = a;
    }

    float acc[8][COG];
#pragma unroll
    for (int j = 0; j < 8; j++)
#pragma unroll
        for (int c = 0; c < COG; c++) acc[j][c] = 0.f;

    const int steps = Cin >> 1;

    auto STAGE = [&](int t, int buf) {
        const float* p = inB + (size_t)(2 * t) * HWin;
#pragma unroll
        for (int r = 0; r < NR; r++)
            if (act[r])
                __builtin_amdgcn_global_load_lds(
                    (gas_ptr)(p + gOff[r]),
                    (las_ptr)(&sIn[buf][lOff[r]]), 16, 0, 0);
        const float* wp2 = w + (size_t)(2 * t) * 9;
#pragma unroll
        for (int r = 0; r < NWR; r++)
            if (wact[r])
                __builtin_amdgcn_global_load_lds(
                    (gas_ptr)(wp2 + wgo[r]),
                    (las_ptr)(&sW[buf][wlo[r]]), 4, 0, 0);
    };

    STAGE(0, 0);
    __syncthreads();
    for (int k = 0; k < steps; k++) {
        const int cur = k & 1, nb = cur ^ 1;
        if (k + 1 < steps) STAGE(k + 1, nb);
        const float* sI = sIn[cur];
        const float* sw = sW[cur];
#pragma unroll
        for (int ci = 0; ci < 2; ci++)
#pragma unroll
            for (int dx = 0; dx < 3; dx++) {
                const float* bp = sI + ci * CI + (8 * ty) * RS + tx + dx;
                float a[10];
#pragma unroll
                for (int j = 0; j < 10; j++) a[j] = bp[j * RS];
#pragma unroll
                for (int dy = 0; dy < 3; dy++) {
                    const float* wp = sw + (ci * 9 + dy * 3 + dx) * COG;
#pragma unroll
                    for (int c = 0; c < COG; c++) {
                        float wv = wp[c];
#pragma unroll
                        for (int j = 0; j < 8; j++)
                            acc[j][c] += a[j + dy] * wv;
                    }
                }
            }
        __syncthreads();
    }

    float* outB = out + (size_t)(b * Cout + cog) * oHp * oWp;
#pragma unroll
    for (int c = 0; c < COG; c++)
#pragma unroll
        for (int j = 0; j < 8; j++)
            outB[(size_t)c * oHp * oWp +
                 (size_t)(tY + 8 * ty + j + oOff) * oWp + tX + tx + oOff] =
                acc[j][c];
    stats_epi<COG, 8, 2>(acc, sRed, part, cog, slotBase, S, tid);
}

// ---------------------------------------------------------------------------
// bnact: FUSED bnfin + float4-vectorized transform (G13: hipcc doesn't
// auto-vectorize; scalar fp32 loads were ~2x slower on ~394 MB of glue
// traffic). Wp is always W+4 and a multiple of 4; planes 16B-aligned.
// part==nullptr -> pure vector memset of the plane (h0p pre-zero; interior
// is fully overwritten by conv0 afterwards).
// ---------------------------------------------------------------------------
__global__ __launch_bounds__(256) void bnact_k(float* __restrict__ p,
                                               const double2* __restrict__ part,
                                               int S, double invN,
                                               const float* __restrict__ g,
                                               const float* __restrict__ bb,
                                               int C, int H, int W,
                                               int Hp, int Wp) {
    __shared__ double2 red[4];
    __shared__ float2 sSS;
    int pc = blockIdx.x;
    int c = pc & (C - 1);
    int tid = threadIdx.x;
    const bool xf = (part != nullptr);
    if (xf) {
        double sum = 0.0, sq = 0.0;
        for (int s = tid; s < S; s += 256) {
            double2 pp = part[(size_t)c * S + s];
            sum += pp.x; sq += pp.y;
        }
#pragma unroll
        for (int off = 32; off; off >>= 1) {
            sum += __shfl_xor(sum, off);
            sq += __shfl_xor(sq, off);
        }
        if ((tid & 63) == 0) red[tid >> 6] = make_double2(sum, sq);
        __syncthreads();
        if (tid == 0) {
            double s2 = 0.0, q2 = 0.0;
#pragma unroll
            for (int wv = 0; wv < 4; wv++) { s2 += red[wv].x; q2 += red[wv].y; }
            double m = s2 * invN;
            double v = q2 * invN - m * m;
            double sc = (double)g[c] / sqrt(v + 1e-5);
            sSS = make_float2((float)sc, (float)((double)bb[c] - m * sc));
        }
        __syncthreads();
    }
    const float2 t = xf ? sSS : make_float2(1.f, 0.f);
    float4* pl4 = reinterpret_cast<float4*>(p + (size_t)pc * Hp * Wp);
    const int wq = Wp >> 2;
    const int n4 = Hp * wq;
    const float4 z4 = make_float4(0.f, 0.f, 0.f, 0.f);
    for (int i = tid; i < n4; i += 256) {
        int y = i / wq, xq = i - y * wq;
        if (!xf || y < 1 || y > H) {          // border rows / memset mode
            pl4[i] = z4;
            continue;
        }
        float4 v = pl4[i];
        float r0 = v.x, r1 = v.y, r2 = v.z, r3 = v.w;
        int x0 = xq << 2;
        r0 = (x0 >= 1 && x0 <= W) ? lrelu(t.x * r0 + t.y) : 0.f;
        r1 = (x0 + 1 <= W)        ? lrelu(t.x * r1 + t.y) : 0.f;   // x0+1>=1 always
        r2 = (x0 + 2 <= W)        ? lrelu(t.x * r2 + t.y) : 0.f;
        r3 = (x0 + 3 <= W)        ? lrelu(t.x * r3 + t.y) : 0.f;
        pl4[i] = make_float4(r0, r1, r2, r3);
    }
}

// ---------------------------------------------------------------------------
// transp: h6 raw (8,256,64,64) + FUSED BN6 finalize (S=32 slots) + lrelu
// -> tok (8,4096,256). Per block: 8 threads/channel reduce 32 slots.
// ---------------------------------------------------------------------------
__global__ __launch_bounds__(256) void transp_k(const float* __restrict__ h6,
                                                const double2* __restrict__ part,
                                                double invN,
                                                const float* __restrict__ g,
                                                const float* __restrict__ bb,
                                                float* __restrict__ tok) {
    __shared__ float sT[32][33];
    __shared__ float2 sSS[32];
    int tid = threadIdx.x;
    int tx = tid & 31, ty = tid >> 5;
    int n0 = blockIdx.x * 32, d0 = blockIdx.y * 32, b = blockIdx.z;
    {
        int d = tid >> 3, s = tid & 7;        // 32 channels x 8 lanes each
        int c = d0 + d;
        double sum = 0.0, sq = 0.0;
#pragma unroll
        for (int i = 0; i < 4; i++) {
            double2 pp = part[(size_t)c * 32 + s + 8 * i];
            sum += pp.x; sq += pp.y;
        }
        sum += __shfl_xor(sum, 4); sq += __shfl_xor(sq, 4);
        sum += __shfl_xor(sum, 2); sq += __shfl_xor(sq, 2);
        sum += __shfl_xor(sum, 1); sq += __shfl_xor(sq, 1);
        if (s == 0) {
            double m = sum * invN;
            double v = sq * invN - m * m;
            double sc = (double)g[c] / sqrt(v + 1e-5);
            sSS[d] = make_float2((float)sc, (float)((double)bb[c] - m * sc));
        }
    }
    __syncthreads();
    const float* hb = h6 + ((size_t)b * 256 + d0) * 4096 + n0;
#pragma unroll
    for (int r = 0; r < 4; r++) {
        int d = ty + 8 * r;
        float2 t = sSS[d];
        sT[d][tx] = lrelu(t.x * hb[d * 4096 + tx] + t.y);
    }
    __syncthreads();
    float* tb = tok + ((size_t)b * 4096 + n0) * 256 + d0;
#pragma unroll
    for (int r = 0; r < 4; r++) {
        int n = ty + 8 * r;
        tb[n * 256 + tx] = sT[tx][n];
    }
}

// ---------------------------------------------------------------------------
// Token stage: gating argmax, selected-expert body slice, ortho, cls MLP.
// ---------------------------------------------------------------------------
__global__ __launch_bounds__(256) void token_k(const float* __restrict__ tok,
                                               const float* __restrict__ wg,
                                               const float* __restrict__ bw,
                                               const float* __restrict__ bb,
                                               const float* __restrict__ ow,
                                               const float* __restrict__ w1,
                                               const float* __restrict__ b1,
                                               const float* __restrict__ w2,
                                               const float* __restrict__ b2,
                                               float* __restrict__ outp) {
    __shared__ float sf[4][256];
    const int tid = threadIdx.x, wave = tid >> 6, l = tid & 63;
    const int t = blockIdx.x * 4 + wave;
    const float4 tv = reinterpret_cast<const float4*>(tok + (size_t)t * 256)[l];
    sf[wave][4 * l + 0] = tv.x; sf[wave][4 * l + 1] = tv.y;
    sf[wave][4 * l + 2] = tv.z; sf[wave][4 * l + 3] = tv.w;

    float lg[12];
#pragma unroll
    for (int e = 0; e < 12; e++) lg[e] = 0.f;
    const float tj[4] = {tv.x, tv.y, tv.z, tv.w};
#pragma unroll
    for (int j = 0; j < 4; j++) {
        const float* wr = wg + (4 * l + j) * 12;
#pragma unroll
        for (int e = 0; e < 12; e++) lg[e] += tj[j] * wr[e];
    }
#pragma unroll
    for (int off = 32; off > 0; off >>= 1) {
#pragma unroll
        for (int e = 0; e < 12; e++) lg[e] += __shfl_xor(lg[e], off);
    }
    int idx = 0; float best = lg[0];
#pragma unroll
    for (int e = 1; e < 12; e++)
        if (lg[e] > best) { best = lg[e]; idx = e; }
    const int cb = idx * 256;

    float f0 = 0.f, f1 = 0.f, f2 = 0.f, f3 = 0.f;
    const float* bwp = bw + cb + 4 * l;
#pragma unroll 4
    for (int d = 0; d < 256; d++) {
        const float td = sf[wave][d];
        const float4 wv = *reinterpret_cast<const float4*>(bwp + (size_t)d * 3072);
        f0 += td * wv.x; f1 += td * wv.y;
        f2 += td * wv.z; f3 += td * wv.w;
    }
    float fj[4] = {f0, f1, f2, f3};
#pragma unroll
    for (int j = 0; j < 4; j++) {
        int jj = cb + 4 * l + j;
        float v = lrelu(fj[j] + bb[jj]);
        v = lrelu(v * ow[jj]);
        sf[wave][4 * l + j] = v;
    }

    float o = 0.f;
    if (l < 32) {
        float h = b1[l];
#pragma unroll 4
        for (int j = 0; j < 256; j++) h += sf[wave][j] * w1[j * 32 + l];
        h = lrelu(h);
        o = h * w2[l];
    }
    o += __shfl_xor(o, 16); o += __shfl_xor(o, 8); o += __shfl_xor(o, 4);
    o += __shfl_xor(o, 2);  o += __shfl_xor(o, 1);
    if (l == 0) outp[t] = o + b2[0];
}

// ---------------------------------------------------------------------------
extern "C" void kernel_launch(void* const* d_in, const int* in_sizes, int n_in,
                              void* d_out, int out_size, void* d_ws, size_t ws_size,
                              hipStream_t stream) {
    const float* x   = (const float*)d_in[0];
    const float* w0  = (const float*)d_in[1];
    const float* b0  = (const float*)d_in[2];
    const float* w1  = (const float*)d_in[3];
    const float* g1  = (const float*)d_in[4];
    const float* be1 = (const float*)d_in[5];
    const float* w2  = (const float*)d_in[6];
    const float* g2  = (const float*)d_in[7];
    const float* be2 = (const float*)d_in[8];
    const float* w3  = (const float*)d_in[9];
    const float* g3  = (const float*)d_in[10];
    const float* be3 = (const float*)d_in[11];
    const float* w4  = (const float*)d_in[12];
    const float* g4  = (const float*)d_in[13];
    const float* be4 = (const float*)d_in[14];
    const float* w5  = (const float*)d_in[15];
    const float* g5  = (const float*)d_in[16];
    const float* be5 = (const float*)d_in[17];
    const float* w6  = (const float*)d_in[18];
    const float* g6  = (const float*)d_in[19];
    const float* be6 = (const float*)d_in[20];
    const float* wg  = (const float*)d_in[21];
    const float* bw  = (const float*)d_in[22];
    const float* bbp = (const float*)d_in[23];
    const float* owp = (const float*)d_in[24];
    const float* cw1 = (const float*)d_in[25];
    const float* cb1 = (const float*)d_in[26];
    const float* cw2 = (const float*)d_in[27];
    const float* cb2 = (const float*)d_in[28];

    char* W = (char*)d_ws;
    double2* part = (double2*)(W + 16384);    // up to 256 KiB of partials

    // Big region @278528 — R1-proven buffer plan (span 105.71 MB).
    char* BIG = W + 278528;
    float* h0p = (float*)(BIG);               // (4,64,258,260) 68.69 MB
    float* h1p = (float*)(BIG + 70287360);    // (8,64,130,132) 35.14 MB
    float* h2p = (float*)(BIG);               // (8,128,130,132) 70.29 MB
    float* h3p = (float*)(BIG + 70287360);    // (8,128,66,68) 18.4 MB
    float* h4p = (float*)(BIG);               // (8,256,66,68) 36.77 MB
    float* h5p = (float*)(BIG + 36765696);    // (8,256,66,68)
    float* h6  = (float*)(BIG);               // (8,256,64,64) 32 MiB
    float* tok = (float*)(BIG + 36765696);    // (8,4096,256) 32 MiB

    // zero h0p planes once (conv0 halves write all interior afterwards)
    bnact_k<<<256, 256, 0, stream>>>(h0p, nullptr, 0, 0.0, nullptr, nullptr,
                                     64, 256, 256, 258, 260);
    // conv0 (padded out) + conv1 per half
    for (int half = 0; half < 2; half++) {
        conv0_k<<<dim3(64, 4, 4), 256, 0, stream>>>(
            x + (size_t)half * 4 * 3 * 65536, w0, b0, h0p);
        c4x4p_k<8><<<dim3(16, 4, 8), 256, 0, stream>>>(
            h0p, w1, h1p + (size_t)half * 4 * 64 * 17160, part, half * 64, 128,
            64, 64, 256, 258, 260, 130, 132, 1);
    }
    // bnact h1p with fused BN1 finalize (S=128)
    bnact_k<<<512, 256, 0, stream>>>(h1p, part, 128, 1.0 / 131072.0, g1, be1,
                                     64, 128, 128, 130, 132);
    // conv2 3x3 (256 thr, 32x64 tiles): 1024 blocks, stats S=64
    c3x3_k<8><<<dim3(8, 8, 16), 256, 0, stream>>>(
        h1p, w2, h2p, part, 0, 64, 64, 128, 128, 130, 132, 130, 132, 1);
    bnact_k<<<1024, 256, 0, stream>>>(h2p, part, 64, 1.0 / 131072.0, g2, be2,
                                      128, 128, 128, 130, 132);
    // conv3 4x4 s2 (256 thr, 32x32 tiles), stats S=32
    c4x4p_k<8><<<dim3(4, 8, 16), 256, 0, stream>>>(
        h2p, w3, h3p, part, 0, 32, 128, 128, 128, 130, 132, 66, 68, 1);
    bnact_k<<<1024, 256, 0, stream>>>(h3p, part, 32, 1.0 / 32768.0, g3, be3,
                                      128, 64, 64, 66, 68);
    // conv4 3x3 (128 thr, 32x32 tiles): 1024 blocks, stats S=32
    c3x3h_k<8><<<dim3(4, 8, 32), 128, 0, stream>>>(
        h3p, w4, h4p, part, 0, 32, 128, 256, 64, 66, 68, 66, 68, 1);
    bnact_k<<<2048, 256, 0, stream>>>(h4p, part, 32, 1.0 / 32768.0, g4, be4,
                                      256, 64, 64, 66, 68);
    // conv5 3x3 (128 thr): 1024 blocks
    c3x3h_k<8><<<dim3(4, 8, 32), 128, 0, stream>>>(
        h4p, w5, h5p, part, 0, 32, 256, 256, 64, 66, 68, 66, 68, 1);
    bnact_k<<<2048, 256, 0, stream>>>(h5p, part, 32, 1.0 / 32768.0, g5, be5,
                                      256, 64, 64, 66, 68);
    // conv6 3x3 (128 thr): h5p -> h6 unpadded, stats S=32
    c3x3h_k<8><<<dim3(4, 8, 32), 128, 0, stream>>>(
        h5p, w6, h6, part, 0, 32, 256, 256, 64, 66, 68, 64, 64, 0);
    // transpose + fused BN6 finalize (S=32) + lrelu -> tok
    transp_k<<<dim3(128, 8, 8), 256, 0, stream>>>(h6, part, 1.0 / 32768.0,
                                                  g6, be6, tok);
    // token stage -> out fp32 (8,4096,1)
    token_k<<<8192, 256, 0, stream>>>(tok, wg, bw, bbp, owp, cw1, cb1, cw2, cb2,
                                      (float*)d_out);
}